// Round 4
// baseline (11223.364 us; speedup 1.0000x reference)
//
#include <hip/hip_runtime.h>

#define H 64
#define MAXW 256        // max windows (scan width)
#define WSH 10          // 1024 nodes per window -> W = ceil(200000/1024) = 196 <= MAXW
#define WNODES (1 << WSH)
#define BINCH 4096      // edges per k_bin block
#define BPT (BINCH / 256)

#define ADD4(a, v) { a.x += v.x; a.y += v.y; a.z += v.z; a.w += v.w; }

// ---------- window counting (LDS-aggregated; ~200 global atomics/block) ----------
__global__ __launch_bounds__(256) void k_wincount(const int* __restrict__ ei, int E,
                                                  int* __restrict__ winS, int* __restrict__ winD) {
    __shared__ int hs[MAXW], hd[MAXW];
    hs[threadIdx.x] = 0; hd[threadIdx.x] = 0;
    __syncthreads();
    int stride = gridDim.x * 256;
    for (int e = blockIdx.x * 256 + threadIdx.x; e < E; e += stride) {
        atomicAdd(&hs[ei[e] >> WSH], 1);
        atomicAdd(&hd[ei[E + e] >> WSH], 1);
    }
    __syncthreads();
    if (hs[threadIdx.x]) atomicAdd(&winS[threadIdx.x], hs[threadIdx.x]);
    if (hd[threadIdx.x]) atomicAdd(&winD[threadIdx.x], hd[threadIdx.x]);
}

// Single block: exclusive scan of both window-count arrays (MAXW wide, zero-padded).
__global__ void k_scan_win(const int* __restrict__ winS, const int* __restrict__ winD,
                           int* __restrict__ baseS, int* __restrict__ baseD,
                           int* __restrict__ curS, int* __restrict__ curD) {
    __shared__ int s[256];
    int tid = threadIdx.x;
    int v = winS[tid];
    s[tid] = v; __syncthreads();
    for (int off = 1; off < 256; off <<= 1) {
        int t = (tid >= off) ? s[tid - off] : 0; __syncthreads();
        s[tid] += t; __syncthreads();
    }
    int ex = s[tid] - v;
    baseS[tid] = ex; curS[tid] = ex;
    if (tid == 255) baseS[256] = s[255];
    __syncthreads();
    v = winD[tid];
    s[tid] = v; __syncthreads();
    for (int off = 1; off < 256; off <<= 1) {
        int t = (tid >= off) ? s[tid - off] : 0; __syncthreads();
        s[tid] += t; __syncthreads();
    }
    ex = s[tid] - v;
    baseD[tid] = ex; curD[tid] = ex;
    if (tid == 255) baseD[256] = s[255];
}

// ---------- bin: LDS counting-sort of a 4096-edge chunk by window, coalesced flush ----------
__global__ __launch_bounds__(256) void k_bin(const int* __restrict__ ei, int E,
                                             int* __restrict__ gcurS, int* __restrict__ gcurD,
                                             int2* __restrict__ bufS, int2* __restrict__ bufD) {
    __shared__ int hist[MAXW];
    __shared__ int lbase[MAXW];
    __shared__ int lcur[MAXW];
    __shared__ int gdelta[MAXW];
    __shared__ int2 rec[BINCH];
    __shared__ unsigned char wid[BINCH];
    __shared__ int sscan[256];

    int tid = threadIdx.x;
    int e0 = blockIdx.x * BINCH;
    int n = min(BINCH, E - e0);

    for (int dir = 0; dir < 2; ++dir) {
        int* gcur = dir ? gcurD : gcurS;
        int2* buf = dir ? bufD : bufS;
        hist[tid] = 0;
        __syncthreads();
        int kk[BPT], vv[BPT];
#pragma unroll
        for (int j = 0; j < BPT; ++j) {
            int idx = tid + j * 256;
            if (idx < n) {
                int e = e0 + idx;
                int a = ei[e], b = ei[E + e];
                kk[j] = dir ? b : a;
                vv[j] = dir ? a : b;
                atomicAdd(&hist[kk[j] >> WSH], 1);
            }
        }
        __syncthreads();
        {   // exclusive scan of hist
            int hv = hist[tid];
            sscan[tid] = hv; __syncthreads();
            for (int off = 1; off < 256; off <<= 1) {
                int t = (tid >= off) ? sscan[tid - off] : 0; __syncthreads();
                sscan[tid] += t; __syncthreads();
            }
            lbase[tid] = sscan[tid] - hv;
            lcur[tid] = lbase[tid];
        }
        __syncthreads();
#pragma unroll
        for (int j = 0; j < BPT; ++j) {
            int idx = tid + j * 256;
            if (idx < n) {
                int w = kk[j] >> WSH;
                int p = atomicAdd(&lcur[w], 1);
                rec[p] = make_int2(kk[j], vv[j]);
                wid[p] = (unsigned char)w;
            }
        }
        __syncthreads();
        {   // reserve one contiguous global chunk per non-empty window
            int c = hist[tid];
            int g = c ? atomicAdd(&gcur[tid], c) : 0;
            gdelta[tid] = g - lbase[tid];
        }
        __syncthreads();
        for (int j = tid; j < n; j += 256) {   // coalesced flush (runs sorted by window)
            int w = wid[j];
            int2 r = rec[j];
            *(long long*)&buf[gdelta[w] + j] = *(long long*)&r;
        }
        __syncthreads();
    }
}

// ---------- fused per-window CSR build with src-range partition ----------
// Each node's adjacency is laid out [srcs < split | srcs >= split]; mid[] marks
// the boundary. This lets the SAGE gather run as two dispatches each touching
// only HALF the src feature array (25.6MB hot set -> L3-resident), which is the
// fix for the measured ~0.9GB/dispatch of L3 gather misses (R2 counters).
__global__ __launch_bounds__(256) void k_build_win(const int2* __restrict__ bufS,
                                                   const int2* __restrict__ bufD,
                                                   const int* __restrict__ baseS,
                                                   const int* __restrict__ baseD,
                                                   int* __restrict__ rpS, int* __restrict__ rpD,
                                                   int* __restrict__ midS, int* __restrict__ midD,
                                                   int* __restrict__ colS, int* __restrict__ colD,
                                                   int Ns, int Nd, int splitS, int splitD, int W) {
    __shared__ int h[WNODES];    // total histogram -> lower-half cursors
    __shared__ int hl[WNODES];   // lower-half histogram -> upper-half cursors
    __shared__ int sscan[256];
    int b = blockIdx.x, tid = threadIdx.x;
    int dir = (b >= W) ? 1 : 0;
    int w = dir ? b - W : b;
    const int2* buf = dir ? bufD : bufS;
    const int* base = dir ? baseD : baseS;
    int* rp = dir ? rpD : rpS;
    int* midp = dir ? midD : midS;
    int* col = dir ? colD : colS;
    int N = dir ? Nd : Ns;
    int split = dir ? splitD : splitS;
    int lo = w << WSH;
    int hi = min(lo + WNODES, N);

    for (int i = tid; i < WNODES; i += 256) { h[i] = 0; hl[i] = 0; }
    __syncthreads();
    int beg = base[w], end = base[w + 1];
    for (int r = beg + tid; r < end; r += 256) {
        int2 rc = buf[r];
        atomicAdd(&h[rc.x - lo], 1);
        if (rc.y < split) atomicAdd(&hl[rc.x - lo], 1);
    }
    __syncthreads();

    // exclusive scan of h[0..1023] (4 elems/thread + 256-wide LDS scan)
    int i0 = tid * 4;
    int v0 = h[i0], v1 = h[i0 + 1], v2 = h[i0 + 2], v3 = h[i0 + 3];
    int t = v0 + v1 + v2 + v3;
    sscan[tid] = t; __syncthreads();
    for (int off = 1; off < 256; off <<= 1) {
        int x = (tid >= off) ? sscan[tid - off] : 0; __syncthreads();
        sscan[tid] += x; __syncthreads();
    }
    int e0 = sscan[tid] - t;
    int e1 = e0 + v0, e2 = e1 + v1, e3 = e2 + v2;
    int l0 = hl[i0], l1 = hl[i0 + 1], l2 = hl[i0 + 2], l3 = hl[i0 + 3];
    int gi = lo + i0;
    if (gi < hi)     { rp[gi]     = beg + e0; midp[gi]     = beg + e0 + l0; }
    if (gi + 1 < hi) { rp[gi + 1] = beg + e1; midp[gi + 1] = beg + e1 + l1; }
    if (gi + 2 < hi) { rp[gi + 2] = beg + e2; midp[gi + 2] = beg + e2 + l2; }
    if (gi + 3 < hi) { rp[gi + 3] = beg + e3; midp[gi + 3] = beg + e3 + l3; }
    if (tid == 255 && hi == N) rp[N] = beg + sscan[255];
    // cursors: h = lower-half (starts at e), hl = upper-half (starts at e + l)
    h[i0] = e0;          h[i0 + 1] = e1;          h[i0 + 2] = e2;          h[i0 + 3] = e3;
    hl[i0] = e0 + l0;    hl[i0 + 1] = e1 + l1;    hl[i0 + 2] = e2 + l2;    hl[i0 + 3] = e3 + l3;
    __syncthreads();

    for (int r = beg + tid; r < end; r += 256) {
        int2 rc = buf[r];
        int idx = rc.x - lo;
        int p = (rc.y < split) ? atomicAdd(&h[idx], 1) : atomicAdd(&hl[idx], 1);
        col[beg + p] = rc.y;
    }
}

// ---------- feature init: 4 nodes per 256-thread block ----------
__global__ __launch_bounds__(256) void k_init_x(const int* __restrict__ uid, const int* __restrict__ rid,
                         const float* __restrict__ recipe_x,
                         const float* __restrict__ user_emb, const float* __restrict__ recipe_emb,
                         const float* __restrict__ lin_w, const float* __restrict__ lin_b,
                         float* __restrict__ x_user, float* __restrict__ x_recipe,
                         int Nu, int Nr) {
    int n = blockIdx.x * 4 + (threadIdx.x >> 6);
    int h = threadIdx.x & 63;
    if (n < Nr) {
        float o = lin_b[h];
#pragma unroll
        for (int k = 0; k < 10; ++k)   // recipe_x addr wave-uniform -> broadcast load
            o = fmaf(recipe_x[(size_t)n * 10 + k], lin_w[k * H + h], o);
        o += recipe_emb[(size_t)rid[n] * H + h];
        x_recipe[(size_t)n * H + h] = o;
    }
    if (n < Nu) {
        x_user[(size_t)n * H + h] = user_emb[(size_t)uid[n] * H + h];
    }
}

// ---------- SAGE phase 1: partial sums over srcs < split ----------
// One 16-lane group per dst node (float4/lane over the 64-float row). Hot set =
// lower half of x_src (25.6MB). Writes partial sums into `out` (scratch until
// phase 2 overwrites it). No LDS, no barrier.
__global__ __launch_bounds__(256, 8) void k_sage_p1(const float* __restrict__ x_src,
                                                    const int* __restrict__ rp,
                                                    const int* __restrict__ mid,
                                                    const int* __restrict__ col,
                                                    float* __restrict__ out, int n_dst) {
    int wave = threadIdx.x >> 6, lane = threadIdx.x & 63;
    int c = lane & 15, g = lane >> 4;
    int n = (blockIdx.x * 4 + wave) * 4 + g;
    if (n >= n_dst) return;
    const float4* xs = (const float4*)x_src;
    int e = rp[n], end = mid[n];
    float4 a0 = make_float4(0.f, 0.f, 0.f, 0.f);
    float4 a1 = a0, a2 = a0, a3 = a0;
    for (; e + 3 < end; e += 4) {
        int r0 = col[e];
        int r1 = col[e + 1];
        int r2 = col[e + 2];
        int r3 = col[e + 3];
        float4 v0 = xs[(r0 << 4) + c];
        float4 v1 = xs[(r1 << 4) + c];
        float4 v2 = xs[(r2 << 4) + c];
        float4 v3 = xs[(r3 << 4) + c];
        ADD4(a0, v0); ADD4(a1, v1); ADD4(a2, v2); ADD4(a3, v3);
    }
    for (; e < end; ++e) {
        int r = col[e];
        float4 v = xs[(r << 4) + c];
        ADD4(a0, v);
    }
    float4 s;
    s.x = (a0.x + a1.x) + (a2.x + a3.x);
    s.y = (a0.y + a1.y) + (a2.y + a3.y);
    s.z = (a0.z + a1.z) + (a2.z + a3.z);
    s.w = (a0.w + a1.w) + (a2.w + a3.w);
    ((float4*)out)[(n << 4) + c] = s;
}

// ---------- SAGE phase 2: srcs >= split, + partial, mean, MLP ----------
// Hot set = upper half of x_src. Reads the phase-1 partial from `out`
// (sequential stream), finishes the mean, runs the epilogue, overwrites out.
// sm/sx are wave-private -> in-wave lgkmcnt handoff instead of __syncthreads.
template <bool RELU>
__global__ __launch_bounds__(256, 8) void k_sage_p2(
    const float* __restrict__ x_src, const float* __restrict__ x_dst,
    const int* __restrict__ rp, const int* __restrict__ mid,
    const int* __restrict__ col,
    const float* __restrict__ Wl, const float* __restrict__ bl,
    const float* __restrict__ Wr, float* __restrict__ out, int n_dst) {
    int wave = threadIdx.x >> 6, lane = threadIdx.x & 63;
    int c = lane & 15, g = lane >> 4;          // group g owns node n0+g
    int n0 = (blockIdx.x * 4 + wave) * 4;
    __shared__ __align__(16) float sm[4][4][H];   // [wave][node][feat] mean  (wave-private)
    __shared__ __align__(16) float sx[4][4][H];   // [wave][node][feat] x_dst (wave-private)

    int n = n0 + g;
    if (n < n_dst) {
        const float4* xs = (const float4*)x_src;
        float4 xd = ((const float4*)x_dst)[(n << 4) + c];          // overlaps gather
        float4 pacc = ((const float4*)out)[(n << 4) + c];          // phase-1 partial
        int beg = rp[n];
        int e = mid[n], end = rp[n + 1];
        float4 a0 = make_float4(0.f, 0.f, 0.f, 0.f);
        float4 a1 = a0, a2 = a0, a3 = a0;
        for (; e + 3 < end; e += 4) {
            int r0 = col[e];
            int r1 = col[e + 1];
            int r2 = col[e + 2];
            int r3 = col[e + 3];
            float4 v0 = xs[(r0 << 4) + c];
            float4 v1 = xs[(r1 << 4) + c];
            float4 v2 = xs[(r2 << 4) + c];
            float4 v3 = xs[(r3 << 4) + c];
            ADD4(a0, v0); ADD4(a1, v1); ADD4(a2, v2); ADD4(a3, v3);
        }
        for (; e < end; ++e) {
            int r = col[e];
            float4 v = xs[(r << 4) + c];
            ADD4(a0, v);
        }
        float inv = 1.0f / fmaxf((float)(end - beg), 1.0f);
        float4 mv;
        mv.x = (pacc.x + (a0.x + a1.x) + (a2.x + a3.x)) * inv;
        mv.y = (pacc.y + (a0.y + a1.y) + (a2.y + a3.y)) * inv;
        mv.z = (pacc.z + (a0.z + a1.z) + (a2.z + a3.z)) * inv;
        mv.w = (pacc.w + (a0.w + a1.w) + (a2.w + a3.w)) * inv;
        *((float4*)&sm[wave][g][c * 4]) = mv;
        *((float4*)&sx[wave][g][c * 4]) = xd;
    }
    // wave-local LDS handoff: drain DS writes, forbid reordering. No s_barrier.
    asm volatile("s_waitcnt lgkmcnt(0)" ::: "memory");
    __builtin_amdgcn_sched_barrier(0);

    if (n0 < n_dst) {
        float bb = bl[lane];
        float o0 = bb, o1 = bb, o2 = bb, o3 = bb;
        const float* m = &sm[wave][0][0];   // 4 rows of H, contiguous
        const float* x = &sx[wave][0][0];
#pragma unroll
        for (int k = 0; k < H; k += 4) {
            float4 m0 = *(const float4*)(m + 0 * H + k);   // ds_read_b128 broadcast
            float4 m1 = *(const float4*)(m + 1 * H + k);
            float4 m2 = *(const float4*)(m + 2 * H + k);
            float4 m3 = *(const float4*)(m + 3 * H + k);
            float4 x0 = *(const float4*)(x + 0 * H + k);
            float4 x1 = *(const float4*)(x + 1 * H + k);
            float4 x2 = *(const float4*)(x + 2 * H + k);
            float4 x3 = *(const float4*)(x + 3 * H + k);
            float wl0 = Wl[(k + 0) * H + lane], wr0 = Wr[(k + 0) * H + lane];
            float wl1 = Wl[(k + 1) * H + lane], wr1 = Wr[(k + 1) * H + lane];
            float wl2 = Wl[(k + 2) * H + lane], wr2 = Wr[(k + 2) * H + lane];
            float wl3 = Wl[(k + 3) * H + lane], wr3 = Wr[(k + 3) * H + lane];
            o0 = fmaf(m0.x, wl0, o0); o0 = fmaf(x0.x, wr0, o0);
            o1 = fmaf(m1.x, wl0, o1); o1 = fmaf(x1.x, wr0, o1);
            o2 = fmaf(m2.x, wl0, o2); o2 = fmaf(x2.x, wr0, o2);
            o3 = fmaf(m3.x, wl0, o3); o3 = fmaf(x3.x, wr0, o3);
            o0 = fmaf(m0.y, wl1, o0); o0 = fmaf(x0.y, wr1, o0);
            o1 = fmaf(m1.y, wl1, o1); o1 = fmaf(x1.y, wr1, o1);
            o2 = fmaf(m2.y, wl1, o2); o2 = fmaf(x2.y, wr1, o2);
            o3 = fmaf(m3.y, wl1, o3); o3 = fmaf(x3.y, wr1, o3);
            o0 = fmaf(m0.z, wl2, o0); o0 = fmaf(x0.z, wr2, o0);
            o1 = fmaf(m1.z, wl2, o1); o1 = fmaf(x1.z, wr2, o1);
            o2 = fmaf(m2.z, wl2, o2); o2 = fmaf(x2.z, wr2, o2);
            o3 = fmaf(m3.z, wl2, o3); o3 = fmaf(x3.z, wr2, o3);
            o0 = fmaf(m0.w, wl3, o0); o0 = fmaf(x0.w, wr3, o0);
            o1 = fmaf(m1.w, wl3, o1); o1 = fmaf(x1.w, wr3, o1);
            o2 = fmaf(m2.w, wl3, o2); o2 = fmaf(x2.w, wr3, o2);
            o3 = fmaf(m3.w, wl3, o3); o3 = fmaf(x3.w, wr3, o3);
        }
        if (RELU) {
            o0 = fmaxf(o0, 0.f); o1 = fmaxf(o1, 0.f);
            o2 = fmaxf(o2, 0.f); o3 = fmaxf(o3, 0.f);
        }
        out[(size_t)n0 * H + lane] = o0;
        if (n0 + 1 < n_dst) out[(size_t)(n0 + 1) * H + lane] = o1;
        if (n0 + 2 < n_dst) out[(size_t)(n0 + 2) * H + lane] = o2;
        if (n0 + 3 < n_dst) out[(size_t)(n0 + 3) * H + lane] = o3;
    }
}

// ---------- classifier: 2 edges per 16-lane group ----------
__global__ __launch_bounds__(256) void k_dot(const float* __restrict__ xu,
                                             const float* __restrict__ xr,
                                             const int* __restrict__ eli,
                                             float* __restrict__ out, int L) {
    long long wv = (blockIdx.x * 256LL + threadIdx.x) >> 6;
    int lane = threadIdx.x & 63;
    int c = lane & 15, g = lane >> 4;
    long long e0 = wv * 8 + (long long)g * 2;
    if (e0 >= L) return;
    bool two = (e0 + 1 < L);
    int a0 = eli[e0];
    int b0 = eli[(long long)L + e0];
    int a1 = two ? eli[e0 + 1] : a0;
    int b1 = two ? eli[(long long)L + e0 + 1] : b0;
    const float4* XU = (const float4*)xu;
    const float4* XR = (const float4*)xr;
    float4 u0 = XU[(a0 << 4) + c];
    float4 r0 = XR[(b0 << 4) + c];
    float4 u1 = XU[(a1 << 4) + c];
    float4 r1 = XR[(b1 << 4) + c];
    float p0 = u0.x * r0.x; p0 = fmaf(u0.y, r0.y, p0); p0 = fmaf(u0.z, r0.z, p0); p0 = fmaf(u0.w, r0.w, p0);
    float p1 = u1.x * r1.x; p1 = fmaf(u1.y, r1.y, p1); p1 = fmaf(u1.z, r1.z, p1); p1 = fmaf(u1.w, r1.w, p1);
#pragma unroll
    for (int off = 1; off < 16; off <<= 1) {
        p0 += __shfl_xor(p0, off);
        p1 += __shfl_xor(p1, off);
    }
    if (c == 0) {
        out[e0] = p0;
        if (two) out[e0 + 1] = p1;
    }
}

extern "C" void kernel_launch(void* const* d_in, const int* in_sizes, int n_in,
                              void* d_out, int out_size, void* d_ws, size_t ws_size,
                              hipStream_t stream) {
    const int*   uid        = (const int*)d_in[0];
    const int*   rid        = (const int*)d_in[1];
    const float* recipe_x   = (const float*)d_in[2];
    const int*   ei         = (const int*)d_in[3];
    const int*   eli        = (const int*)d_in[4];
    const float* user_emb   = (const float*)d_in[5];
    const float* recipe_emb = (const float*)d_in[6];
    const float* lin_w      = (const float*)d_in[7];
    const float* lin_b      = (const float*)d_in[8];
    const float* Wl         = (const float*)d_in[9];
    const float* bl         = (const float*)d_in[10];
    const float* Wr         = (const float*)d_in[11];

    const int Nu = in_sizes[0], Nr = in_sizes[1];
    const int E = in_sizes[3] / 2, L = in_sizes[4] / 2;
    const int nmax = (Nu > Nr) ? Nu : Nr;
    const int W = ((nmax - 1) >> WSH) + 1;   // 196 for N=200000

    char* ws = (char*)d_ws;
    size_t off = 0;
    auto alloc = [&](size_t bytes) -> char* {
        char* p = ws + off;
        off += (bytes + 255) & ~(size_t)255;
        return p;
    };
    float* x_user   = (float*)alloc((size_t)Nu * H * 4);
    float* x_recipe = (float*)alloc((size_t)Nr * H * 4);
    // overlay: y buffers (needed from sage on) share space with bin buffers (dead by then)
    size_t ybytes  = ((size_t)Nu + Nr) * H * 4;
    size_t bbytes  = (size_t)E * 8 * 2;
    char* region   = alloc(ybytes > bbytes ? ybytes : bbytes);
    float* y_user   = (float*)region;
    float* y_recipe = (float*)(region + (size_t)Nu * H * 4);
    int2* bufS = (int2*)region;
    int2* bufD = (int2*)(region + (size_t)E * 8);
    int* rp_src  = (int*)alloc((size_t)(Nu + 1) * 4);
    int* rp_dst  = (int*)alloc((size_t)(Nr + 1) * 4);
    int* mid_src = (int*)alloc((size_t)Nu * 4);
    int* mid_dst = (int*)alloc((size_t)Nr * 4);
    int* col_src = (int*)alloc((size_t)E * 4);
    int* col_dst = (int*)alloc((size_t)E * 4);
    int* winS  = (int*)alloc(MAXW * 4);      // winS..winD adjacent: one memset
    int* winD  = (int*)alloc(MAXW * 4);
    int* baseS = (int*)alloc((MAXW + 1) * 4);
    int* baseD = (int*)alloc((MAXW + 1) * 4);
    int* curS  = (int*)alloc(MAXW * 4);
    int* curD  = (int*)alloc(MAXW * 4);
    (void)ws_size; (void)n_in; (void)out_size;

    // zero window counters (ws is poisoned 0xAA)
    hipMemsetAsync(winS, 0, (size_t)2 * MAXW * 4, stream);

    // CSR build: count -> scan -> bin -> fused per-window (hist+scan+rp/mid+scatter)
    k_wincount<<<1024, 256, 0, stream>>>(ei, E, winS, winD);
    k_scan_win<<<1, 256, 0, stream>>>(winS, winD, baseS, baseD, curS, curD);
    k_bin<<<(E + BINCH - 1) / BINCH, 256, 0, stream>>>(ei, E, curS, curD, bufS, bufD);
    // colS holds recipe ids (split Nr/2); colD holds user ids (split Nu/2)
    k_build_win<<<2 * W, 256, 0, stream>>>(bufS, bufD, baseS, baseD,
                                           rp_src, rp_dst, mid_src, mid_dst,
                                           col_src, col_dst, Nu, Nr, Nr / 2, Nu / 2, W);

    // initial features
    k_init_x<<<(nmax + 3) / 4, 256, 0, stream>>>(uid, rid, recipe_x, user_emb, recipe_emb,
                                                 lin_w, lin_b, x_user, x_recipe, Nu, Nr);

    int nbR = (Nr + 15) / 16, nbU = (Nu + 15) / 16;
    // layer 0 (+ReLU): each direction split into two src-range phases
    k_sage_p1<<<nbR, 256, 0, stream>>>(x_user, rp_dst, mid_dst, col_dst, y_recipe, Nr);
    k_sage_p2<true><<<nbR, 256, 0, stream>>>(x_user, x_recipe, rp_dst, mid_dst, col_dst,
                                             Wl + 0 * H * H, bl + 0 * H, Wr + 0 * H * H,
                                             y_recipe, Nr);
    k_sage_p1<<<nbU, 256, 0, stream>>>(x_recipe, rp_src, mid_src, col_src, y_user, Nu);
    k_sage_p2<true><<<nbU, 256, 0, stream>>>(x_recipe, x_user, rp_src, mid_src, col_src,
                                             Wl + 1 * H * H, bl + 1 * H, Wr + 1 * H * H,
                                             y_user, Nu);
    // layer 1 (no ReLU)
    k_sage_p1<<<nbR, 256, 0, stream>>>(y_user, rp_dst, mid_dst, col_dst, x_recipe, Nr);
    k_sage_p2<false><<<nbR, 256, 0, stream>>>(y_user, y_recipe, rp_dst, mid_dst, col_dst,
                                              Wl + 2 * H * H, bl + 2 * H, Wr + 2 * H * H,
                                              x_recipe, Nr);
    k_sage_p1<<<nbU, 256, 0, stream>>>(y_recipe, rp_src, mid_src, col_src, x_user, Nu);
    k_sage_p2<false><<<nbU, 256, 0, stream>>>(y_recipe, y_user, rp_src, mid_src, col_src,
                                              Wl + 3 * H * H, bl + 3 * H, Wr + 3 * H * H,
                                              x_user, Nu);

    // classifier: 32 edges per block
    long long nblk = ((long long)L + 31) / 32;
    k_dot<<<(int)nblk, 256, 0, stream>>>(x_user, x_recipe, eli, (float*)d_out, L);
}

// Round 5
// 1117.716 us; speedup vs baseline: 10.0413x; 10.0413x over previous
//
#include <hip/hip_runtime.h>

#define H 64
#define MAXW 256        // max windows (scan width)
#define WSH 10          // 1024 nodes per window -> W = ceil(200000/1024) = 196 <= MAXW
#define WNODES (1 << WSH)
#define BINCH 4096      // edges per k_bin block
#define BPT (BINCH / 256)

#define ADD4(a, v) { a.x += v.x; a.y += v.y; a.z += v.z; a.w += v.w; }

// ---------- window counting (LDS-aggregated; ~200 global atomics/block) ----------
__global__ __launch_bounds__(256) void k_wincount(const int* __restrict__ ei, int E,
                                                  int* __restrict__ winS, int* __restrict__ winD) {
    __shared__ int hs[MAXW], hd[MAXW];
    hs[threadIdx.x] = 0; hd[threadIdx.x] = 0;
    __syncthreads();
    int stride = gridDim.x * 256;
    for (int e = blockIdx.x * 256 + threadIdx.x; e < E; e += stride) {
        atomicAdd(&hs[ei[e] >> WSH], 1);
        atomicAdd(&hd[ei[E + e] >> WSH], 1);
    }
    __syncthreads();
    if (hs[threadIdx.x]) atomicAdd(&winS[threadIdx.x], hs[threadIdx.x]);
    if (hd[threadIdx.x]) atomicAdd(&winD[threadIdx.x], hd[threadIdx.x]);
}

// Single block: exclusive scan of both window-count arrays (MAXW wide, zero-padded).
__global__ void k_scan_win(const int* __restrict__ winS, const int* __restrict__ winD,
                           int* __restrict__ baseS, int* __restrict__ baseD,
                           int* __restrict__ curS, int* __restrict__ curD) {
    __shared__ int s[256];
    int tid = threadIdx.x;
    int v = winS[tid];
    s[tid] = v; __syncthreads();
    for (int off = 1; off < 256; off <<= 1) {
        int t = (tid >= off) ? s[tid - off] : 0; __syncthreads();
        s[tid] += t; __syncthreads();
    }
    int ex = s[tid] - v;
    baseS[tid] = ex; curS[tid] = ex;
    if (tid == 255) baseS[256] = s[255];
    __syncthreads();
    v = winD[tid];
    s[tid] = v; __syncthreads();
    for (int off = 1; off < 256; off <<= 1) {
        int t = (tid >= off) ? s[tid - off] : 0; __syncthreads();
        s[tid] += t; __syncthreads();
    }
    ex = s[tid] - v;
    baseD[tid] = ex; curD[tid] = ex;
    if (tid == 255) baseD[256] = s[255];
}

// ---------- bin: LDS counting-sort of a 4096-edge chunk by window, coalesced flush ----------
__global__ __launch_bounds__(256) void k_bin(const int* __restrict__ ei, int E,
                                             int* __restrict__ gcurS, int* __restrict__ gcurD,
                                             int2* __restrict__ bufS, int2* __restrict__ bufD) {
    __shared__ int hist[MAXW];
    __shared__ int lbase[MAXW];
    __shared__ int lcur[MAXW];
    __shared__ int gdelta[MAXW];
    __shared__ int2 rec[BINCH];
    __shared__ unsigned char wid[BINCH];
    __shared__ int sscan[256];

    int tid = threadIdx.x;
    int e0 = blockIdx.x * BINCH;
    int n = min(BINCH, E - e0);

    for (int dir = 0; dir < 2; ++dir) {
        int* gcur = dir ? gcurD : gcurS;
        int2* buf = dir ? bufD : bufS;
        hist[tid] = 0;
        __syncthreads();
        int kk[BPT], vv[BPT];
#pragma unroll
        for (int j = 0; j < BPT; ++j) {
            int idx = tid + j * 256;
            if (idx < n) {
                int e = e0 + idx;
                int a = ei[e], b = ei[E + e];
                kk[j] = dir ? b : a;
                vv[j] = dir ? a : b;
                atomicAdd(&hist[kk[j] >> WSH], 1);
            }
        }
        __syncthreads();
        {   // exclusive scan of hist
            int hv = hist[tid];
            sscan[tid] = hv; __syncthreads();
            for (int off = 1; off < 256; off <<= 1) {
                int t = (tid >= off) ? sscan[tid - off] : 0; __syncthreads();
                sscan[tid] += t; __syncthreads();
            }
            lbase[tid] = sscan[tid] - hv;
            lcur[tid] = lbase[tid];
        }
        __syncthreads();
#pragma unroll
        for (int j = 0; j < BPT; ++j) {
            int idx = tid + j * 256;
            if (idx < n) {
                int w = kk[j] >> WSH;
                int p = atomicAdd(&lcur[w], 1);
                rec[p] = make_int2(kk[j], vv[j]);
                wid[p] = (unsigned char)w;
            }
        }
        __syncthreads();
        {   // reserve one contiguous global chunk per non-empty window
            int c = hist[tid];
            int g = c ? atomicAdd(&gcur[tid], c) : 0;
            gdelta[tid] = g - lbase[tid];
        }
        __syncthreads();
        for (int j = tid; j < n; j += 256) {   // coalesced flush (runs sorted by window)
            int w = wid[j];
            int2 r = rec[j];
            *(long long*)&buf[gdelta[w] + j] = *(long long*)&r;
        }
        __syncthreads();
    }
}

// ---------- fused per-window CSR build: histogram -> LDS scan -> rp -> scatter ----------
__global__ __launch_bounds__(256) void k_build_win(const int2* __restrict__ bufS,
                                                   const int2* __restrict__ bufD,
                                                   const int* __restrict__ baseS,
                                                   const int* __restrict__ baseD,
                                                   int* __restrict__ rpS, int* __restrict__ rpD,
                                                   int* __restrict__ colS, int* __restrict__ colD,
                                                   int Ns, int Nd, int W) {
    __shared__ int h[WNODES];
    __shared__ int sscan[256];
    int b = blockIdx.x, tid = threadIdx.x;
    int dir = (b >= W) ? 1 : 0;
    int w = dir ? b - W : b;
    const int2* buf = dir ? bufD : bufS;
    const int* base = dir ? baseD : baseS;
    int* rp = dir ? rpD : rpS;
    int* col = dir ? colD : colS;
    int N = dir ? Nd : Ns;
    int lo = w << WSH;
    int hi = min(lo + WNODES, N);

    for (int i = tid; i < WNODES; i += 256) h[i] = 0;
    __syncthreads();
    int beg = base[w], end = base[w + 1];
    for (int r = beg + tid; r < end; r += 256)
        atomicAdd(&h[buf[r].x - lo], 1);
    __syncthreads();

    // exclusive scan of h[0..1023] (4 elems/thread + 256-wide LDS scan)
    int i0 = tid * 4;
    int v0 = h[i0], v1 = h[i0 + 1], v2 = h[i0 + 2], v3 = h[i0 + 3];
    int t = v0 + v1 + v2 + v3;
    sscan[tid] = t; __syncthreads();
    for (int off = 1; off < 256; off <<= 1) {
        int x = (tid >= off) ? sscan[tid - off] : 0; __syncthreads();
        sscan[tid] += x; __syncthreads();
    }
    int e0 = sscan[tid] - t;
    int e1 = e0 + v0, e2 = e1 + v1, e3 = e2 + v2;
    h[i0] = e0; h[i0 + 1] = e1; h[i0 + 2] = e2; h[i0 + 3] = e3;  // cursors
    int gi = lo + i0;
    if (gi < hi) rp[gi] = beg + e0;
    if (gi + 1 < hi) rp[gi + 1] = beg + e1;
    if (gi + 2 < hi) rp[gi + 2] = beg + e2;
    if (gi + 3 < hi) rp[gi + 3] = beg + e3;
    if (tid == 255 && hi == N) rp[N] = beg + sscan[255];
    __syncthreads();

    for (int r = beg + tid; r < end; r += 256) {
        int2 rc = buf[r];
        int p = atomicAdd(&h[rc.x - lo], 1);
        col[beg + p] = rc.y;
    }
}

// ---------- feature init: 4 nodes per 256-thread block ----------
__global__ __launch_bounds__(256) void k_init_x(const int* __restrict__ uid, const int* __restrict__ rid,
                         const float* __restrict__ recipe_x,
                         const float* __restrict__ user_emb, const float* __restrict__ recipe_emb,
                         const float* __restrict__ lin_w, const float* __restrict__ lin_b,
                         float* __restrict__ x_user, float* __restrict__ x_recipe,
                         int Nu, int Nr) {
    int n = blockIdx.x * 4 + (threadIdx.x >> 6);
    int h = threadIdx.x & 63;
    if (n < Nr) {
        float o = lin_b[h];
#pragma unroll
        for (int k = 0; k < 10; ++k)   // recipe_x addr wave-uniform -> broadcast load
            o = fmaf(recipe_x[(size_t)n * 10 + k], lin_w[k * H + h], o);
        o += recipe_emb[(size_t)rid[n] * H + h];
        x_recipe[(size_t)n * H + h] = o;
    }
    if (n < Nu) {
        x_user[(size_t)n * H + h] = user_emb[(size_t)uid[n] * H + h];
    }
}

// ---------- SAGE layer (dual direction in one launch) ----------
// One 16-lane group per dst node (4 independent latency chains/wave; no block
// barrier: sm/sx are wave-private, lgkmcnt(0)+sched_barrier orders the in-wave
// LDS handoff). Epilogue: SCALAR wl/wr loop — R3/R4 showed the float4-unrolled
// variant spills to scratch (VGPR report 32-40 vs ~58 live) and scratch RMW
// traffic explodes FETCH/WRITE to ~8GB/dir; scalar form is VGPR-lean (36).
// R5 change vs R2: launch_bounds 6->8 waves/SIMD. R2's Occupancy=74% was
// exactly the (256,6) cap; VGPR 36 <= 64 so 8 waves fit. +33% waves in flight
// attacks the latency-bound regime (neither VALU 60% nor HBM 44% saturated).
template <bool RELU>
__global__ __launch_bounds__(256, 8) void k_sage2(
    const float* __restrict__ xsA, const float* __restrict__ xdA,
    const int* __restrict__ rpA, const int* __restrict__ colA,
    const float* __restrict__ WlA, const float* __restrict__ blA,
    const float* __restrict__ WrA, float* __restrict__ outA, int ndA, int nbA,
    const float* __restrict__ xsB, const float* __restrict__ xdB,
    const int* __restrict__ rpB, const int* __restrict__ colB,
    const float* __restrict__ WlB, const float* __restrict__ blB,
    const float* __restrict__ WrB, float* __restrict__ outB, int ndB) {
    const float* x_src; const float* x_dst; const int* rp; const int* col;
    const float* Wl; const float* bl; const float* Wr; float* out;
    int n_dst, bid;
    if (blockIdx.x < (unsigned)nbA) {
        x_src = xsA; x_dst = xdA; rp = rpA; col = colA;
        Wl = WlA; bl = blA; Wr = WrA; out = outA; n_dst = ndA; bid = blockIdx.x;
    } else {
        x_src = xsB; x_dst = xdB; rp = rpB; col = colB;
        Wl = WlB; bl = blB; Wr = WrB; out = outB; n_dst = ndB; bid = blockIdx.x - nbA;
    }

    int wave = threadIdx.x >> 6, lane = threadIdx.x & 63;
    int c = lane & 15, g = lane >> 4;          // group g owns node n0+g
    int n0 = (bid * 4 + wave) * 4;
    __shared__ float sm[4][4][H];   // [wave][node][feature] mean   (wave-private)
    __shared__ float sx[4][4][H];   // [wave][node][feature] x_dst  (wave-private)

    int n = n0 + g;
    if (n < n_dst) {
        const float4* xs = (const float4*)x_src;
        // x_dst row: issued first, overlaps rp/col/gather latency
        float4 xd = ((const float4*)x_dst)[(n << 4) + c];
        int beg = rp[n], end = rp[n + 1];
        float4 a0 = make_float4(0.f, 0.f, 0.f, 0.f);
        float4 a1 = a0, a2 = a0, a3 = a0;
        int e = beg;
        for (; e + 7 < end; e += 8) {           // 8 loads in flight per group
            int r0 = col[e];
            int r1 = col[e + 1];
            int r2 = col[e + 2];
            int r3 = col[e + 3];
            int r4 = col[e + 4];
            int r5 = col[e + 5];
            int r6 = col[e + 6];
            int r7 = col[e + 7];
            float4 v0 = xs[(r0 << 4) + c];
            float4 v1 = xs[(r1 << 4) + c];
            float4 v2 = xs[(r2 << 4) + c];
            float4 v3 = xs[(r3 << 4) + c];
            float4 v4 = xs[(r4 << 4) + c];
            float4 v5 = xs[(r5 << 4) + c];
            float4 v6 = xs[(r6 << 4) + c];
            float4 v7 = xs[(r7 << 4) + c];
            ADD4(a0, v0); ADD4(a1, v1); ADD4(a2, v2); ADD4(a3, v3);
            ADD4(a0, v4); ADD4(a1, v5); ADD4(a2, v6); ADD4(a3, v7);
        }
        for (; e + 3 < end; e += 4) {
            int r0 = col[e];
            int r1 = col[e + 1];
            int r2 = col[e + 2];
            int r3 = col[e + 3];
            float4 v0 = xs[(r0 << 4) + c];
            float4 v1 = xs[(r1 << 4) + c];
            float4 v2 = xs[(r2 << 4) + c];
            float4 v3 = xs[(r3 << 4) + c];
            ADD4(a0, v0); ADD4(a1, v1); ADD4(a2, v2); ADD4(a3, v3);
        }
        for (; e < end; ++e) {
            int r = col[e];
            float4 v = xs[(r << 4) + c];
            ADD4(a0, v);
        }
        float inv = 1.0f / fmaxf((float)(end - beg), 1.0f);
        float4 mv;
        mv.x = ((a0.x + a1.x) + (a2.x + a3.x)) * inv;
        mv.y = ((a0.y + a1.y) + (a2.y + a3.y)) * inv;
        mv.z = ((a0.z + a1.z) + (a2.z + a3.z)) * inv;
        mv.w = ((a0.w + a1.w) + (a2.w + a3.w)) * inv;
        *((float4*)&sm[wave][g][c * 4]) = mv;
        *((float4*)&sx[wave][g][c * 4]) = xd;
    }
    // wave-local LDS handoff: drain DS writes, forbid reordering. No s_barrier.
    asm volatile("s_waitcnt lgkmcnt(0)" ::: "memory");
    __builtin_amdgcn_sched_barrier(0);

    if (n0 < n_dst) {
        float bb = bl[lane];
        float o0 = bb, o1 = bb, o2 = bb, o3 = bb;
        const float* m = &sm[wave][0][0];   // 4 rows of H, contiguous
        const float* x = &sx[wave][0][0];
#pragma unroll 4
        for (int k = 0; k < H; ++k) {
            float wl = Wl[k * H + lane];    // one 256B L1 load serves 4 nodes
            float wr = Wr[k * H + lane];
            o0 = fmaf(m[0 * H + k], wl, o0); o0 = fmaf(x[0 * H + k], wr, o0);
            o1 = fmaf(m[1 * H + k], wl, o1); o1 = fmaf(x[1 * H + k], wr, o1);
            o2 = fmaf(m[2 * H + k], wl, o2); o2 = fmaf(x[2 * H + k], wr, o2);
            o3 = fmaf(m[3 * H + k], wl, o3); o3 = fmaf(x[3 * H + k], wr, o3);
        }
        if (RELU) {
            o0 = fmaxf(o0, 0.f); o1 = fmaxf(o1, 0.f);
            o2 = fmaxf(o2, 0.f); o3 = fmaxf(o3, 0.f);
        }
        out[(size_t)n0 * H + lane] = o0;
        if (n0 + 1 < n_dst) out[(size_t)(n0 + 1) * H + lane] = o1;
        if (n0 + 2 < n_dst) out[(size_t)(n0 + 2) * H + lane] = o2;
        if (n0 + 3 < n_dst) out[(size_t)(n0 + 3) * H + lane] = o3;
    }
}

// ---------- classifier: 2 edges per 16-lane group ----------
__global__ __launch_bounds__(256) void k_dot(const float* __restrict__ xu,
                                             const float* __restrict__ xr,
                                             const int* __restrict__ eli,
                                             float* __restrict__ out, int L) {
    long long wv = (blockIdx.x * 256LL + threadIdx.x) >> 6;
    int lane = threadIdx.x & 63;
    int c = lane & 15, g = lane >> 4;
    long long e0 = wv * 8 + (long long)g * 2;
    if (e0 >= L) return;
    bool two = (e0 + 1 < L);
    int a0 = eli[e0];
    int b0 = eli[(long long)L + e0];
    int a1 = two ? eli[e0 + 1] : a0;
    int b1 = two ? eli[(long long)L + e0 + 1] : b0;
    const float4* XU = (const float4*)xu;
    const float4* XR = (const float4*)xr;
    float4 u0 = XU[(a0 << 4) + c];
    float4 r0 = XR[(b0 << 4) + c];
    float4 u1 = XU[(a1 << 4) + c];
    float4 r1 = XR[(b1 << 4) + c];
    float p0 = u0.x * r0.x; p0 = fmaf(u0.y, r0.y, p0); p0 = fmaf(u0.z, r0.z, p0); p0 = fmaf(u0.w, r0.w, p0);
    float p1 = u1.x * r1.x; p1 = fmaf(u1.y, r1.y, p1); p1 = fmaf(u1.z, r1.z, p1); p1 = fmaf(u1.w, r1.w, p1);
#pragma unroll
    for (int off = 1; off < 16; off <<= 1) {
        p0 += __shfl_xor(p0, off);
        p1 += __shfl_xor(p1, off);
    }
    if (c == 0) {
        out[e0] = p0;
        if (two) out[e0 + 1] = p1;
    }
}

extern "C" void kernel_launch(void* const* d_in, const int* in_sizes, int n_in,
                              void* d_out, int out_size, void* d_ws, size_t ws_size,
                              hipStream_t stream) {
    const int*   uid        = (const int*)d_in[0];
    const int*   rid        = (const int*)d_in[1];
    const float* recipe_x   = (const float*)d_in[2];
    const int*   ei         = (const int*)d_in[3];
    const int*   eli        = (const int*)d_in[4];
    const float* user_emb   = (const float*)d_in[5];
    const float* recipe_emb = (const float*)d_in[6];
    const float* lin_w      = (const float*)d_in[7];
    const float* lin_b      = (const float*)d_in[8];
    const float* Wl         = (const float*)d_in[9];
    const float* bl         = (const float*)d_in[10];
    const float* Wr         = (const float*)d_in[11];

    const int Nu = in_sizes[0], Nr = in_sizes[1];
    const int E = in_sizes[3] / 2, L = in_sizes[4] / 2;
    const int nmax = (Nu > Nr) ? Nu : Nr;
    const int W = ((nmax - 1) >> WSH) + 1;   // 196 for N=200000

    char* ws = (char*)d_ws;
    size_t off = 0;
    auto alloc = [&](size_t bytes) -> char* {
        char* p = ws + off;
        off += (bytes + 255) & ~(size_t)255;
        return p;
    };
    float* x_user   = (float*)alloc((size_t)Nu * H * 4);
    float* x_recipe = (float*)alloc((size_t)Nr * H * 4);
    // overlay: y buffers (needed from sage on) share space with bin buffers (dead by then)
    size_t ybytes  = ((size_t)Nu + Nr) * H * 4;
    size_t bbytes  = (size_t)E * 8 * 2;
    char* region   = alloc(ybytes > bbytes ? ybytes : bbytes);
    float* y_user   = (float*)region;
    float* y_recipe = (float*)(region + (size_t)Nu * H * 4);
    int2* bufS = (int2*)region;
    int2* bufD = (int2*)(region + (size_t)E * 8);
    int* rp_src  = (int*)alloc((size_t)(Nu + 1) * 4);
    int* rp_dst  = (int*)alloc((size_t)(Nr + 1) * 4);
    int* col_src = (int*)alloc((size_t)E * 4);
    int* col_dst = (int*)alloc((size_t)E * 4);
    int* winS  = (int*)alloc(MAXW * 4);      // winS..winD adjacent: one memset
    int* winD  = (int*)alloc(MAXW * 4);
    int* baseS = (int*)alloc((MAXW + 1) * 4);
    int* baseD = (int*)alloc((MAXW + 1) * 4);
    int* curS  = (int*)alloc(MAXW * 4);
    int* curD  = (int*)alloc(MAXW * 4);
    (void)ws_size; (void)n_in; (void)out_size;

    // zero window counters (ws is poisoned 0xAA)
    hipMemsetAsync(winS, 0, (size_t)2 * MAXW * 4, stream);

    // CSR build: count -> scan -> bin -> fused per-window (deg+scan+scatter)
    k_wincount<<<1024, 256, 0, stream>>>(ei, E, winS, winD);
    k_scan_win<<<1, 256, 0, stream>>>(winS, winD, baseS, baseD, curS, curD);
    k_bin<<<(E + BINCH - 1) / BINCH, 256, 0, stream>>>(ei, E, curS, curD, bufS, bufD);
    k_build_win<<<2 * W, 256, 0, stream>>>(bufS, bufD, baseS, baseD,
                                           rp_src, rp_dst, col_src, col_dst, Nu, Nr, W);

    // initial features
    k_init_x<<<(nmax + 3) / 4, 256, 0, stream>>>(uid, rid, recipe_x, user_emb, recipe_emb,
                                                 lin_w, lin_b, x_user, x_recipe, Nu, Nr);

    int nbR = (Nr + 15) / 16, nbU = (Nu + 15) / 16;
    // layer 0 (+ReLU): both directions in one launch
    k_sage2<true><<<nbR + nbU, 256, 0, stream>>>(
        x_user, x_recipe, rp_dst, col_dst, Wl + 0 * H * H, bl + 0 * H, Wr + 0 * H * H, y_recipe, Nr, nbR,
        x_recipe, x_user, rp_src, col_src, Wl + 1 * H * H, bl + 1 * H, Wr + 1 * H * H, y_user, Nu);
    // layer 1 (no ReLU)
    k_sage2<false><<<nbR + nbU, 256, 0, stream>>>(
        y_user, y_recipe, rp_dst, col_dst, Wl + 2 * H * H, bl + 2 * H, Wr + 2 * H * H, x_recipe, Nr, nbR,
        y_recipe, y_user, rp_src, col_src, Wl + 3 * H * H, bl + 3 * H, Wr + 3 * H * H, x_user, Nu);

    // classifier: 32 edges per block
    long long nblk = ((long long)L + 31) / 32;
    k_dot<<<(int)nblk, 256, 0, stream>>>(x_user, x_recipe, eli, (float*)d_out, L);
}

// Round 7
// 970.101 us; speedup vs baseline: 11.5693x; 1.1522x over previous
//
#include <hip/hip_runtime.h>
#include <hip/hip_fp16.h>

#define H 64
#define MAXW 256        // max windows (scan width)
#define WSH 10          // 1024 nodes per window -> W = ceil(200000/1024) = 196 <= MAXW
#define WNODES (1 << WSH)
#define BINCH 4096      // edges per k_bin block
#define BPT (BINCH / 256)

// ---------- window counting (LDS-aggregated; ~200 global atomics/block) ----------
__global__ __launch_bounds__(256) void k_wincount(const int* __restrict__ ei, int E,
                                                  int* __restrict__ winS, int* __restrict__ winD) {
    __shared__ int hs[MAXW], hd[MAXW];
    hs[threadIdx.x] = 0; hd[threadIdx.x] = 0;
    __syncthreads();
    int stride = gridDim.x * 256;
    for (int e = blockIdx.x * 256 + threadIdx.x; e < E; e += stride) {
        atomicAdd(&hs[ei[e] >> WSH], 1);
        atomicAdd(&hd[ei[E + e] >> WSH], 1);
    }
    __syncthreads();
    if (hs[threadIdx.x]) atomicAdd(&winS[threadIdx.x], hs[threadIdx.x]);
    if (hd[threadIdx.x]) atomicAdd(&winD[threadIdx.x], hd[threadIdx.x]);
}

// Single block: exclusive scan of both window-count arrays (MAXW wide, zero-padded).
__global__ void k_scan_win(const int* __restrict__ winS, const int* __restrict__ winD,
                           int* __restrict__ baseS, int* __restrict__ baseD,
                           int* __restrict__ curS, int* __restrict__ curD) {
    __shared__ int s[256];
    int tid = threadIdx.x;
    int v = winS[tid];
    s[tid] = v; __syncthreads();
    for (int off = 1; off < 256; off <<= 1) {
        int t = (tid >= off) ? s[tid - off] : 0; __syncthreads();
        s[tid] += t; __syncthreads();
    }
    int ex = s[tid] - v;
    baseS[tid] = ex; curS[tid] = ex;
    if (tid == 255) baseS[256] = s[255];
    __syncthreads();
    v = winD[tid];
    s[tid] = v; __syncthreads();
    for (int off = 1; off < 256; off <<= 1) {
        int t = (tid >= off) ? s[tid - off] : 0; __syncthreads();
        s[tid] += t; __syncthreads();
    }
    ex = s[tid] - v;
    baseD[tid] = ex; curD[tid] = ex;
    if (tid == 255) baseD[256] = s[255];
}

// ---------- bin: LDS counting-sort of a 4096-edge chunk by window, coalesced flush ----------
__global__ __launch_bounds__(256) void k_bin(const int* __restrict__ ei, int E,
                                             int* __restrict__ gcurS, int* __restrict__ gcurD,
                                             int2* __restrict__ bufS, int2* __restrict__ bufD) {
    __shared__ int hist[MAXW];
    __shared__ int lbase[MAXW];
    __shared__ int lcur[MAXW];
    __shared__ int gdelta[MAXW];
    __shared__ int2 rec[BINCH];
    __shared__ unsigned char wid[BINCH];
    __shared__ int sscan[256];

    int tid = threadIdx.x;
    int e0 = blockIdx.x * BINCH;
    int n = min(BINCH, E - e0);

    for (int dir = 0; dir < 2; ++dir) {
        int* gcur = dir ? gcurD : gcurS;
        int2* buf = dir ? bufD : bufS;
        hist[tid] = 0;
        __syncthreads();
        int kk[BPT], vv[BPT];
#pragma unroll
        for (int j = 0; j < BPT; ++j) {
            int idx = tid + j * 256;
            if (idx < n) {
                int e = e0 + idx;
                int a = ei[e], b = ei[E + e];
                kk[j] = dir ? b : a;
                vv[j] = dir ? a : b;
                atomicAdd(&hist[kk[j] >> WSH], 1);
            }
        }
        __syncthreads();
        {   // exclusive scan of hist
            int hv = hist[tid];
            sscan[tid] = hv; __syncthreads();
            for (int off = 1; off < 256; off <<= 1) {
                int t = (tid >= off) ? sscan[tid - off] : 0; __syncthreads();
                sscan[tid] += t; __syncthreads();
            }
            lbase[tid] = sscan[tid] - hv;
            lcur[tid] = lbase[tid];
        }
        __syncthreads();
#pragma unroll
        for (int j = 0; j < BPT; ++j) {
            int idx = tid + j * 256;
            if (idx < n) {
                int w = kk[j] >> WSH;
                int p = atomicAdd(&lcur[w], 1);
                rec[p] = make_int2(kk[j], vv[j]);
                wid[p] = (unsigned char)w;
            }
        }
        __syncthreads();
        {   // reserve one contiguous global chunk per non-empty window
            int c = hist[tid];
            int g = c ? atomicAdd(&gcur[tid], c) : 0;
            gdelta[tid] = g - lbase[tid];
        }
        __syncthreads();
        for (int j = tid; j < n; j += 256) {   // coalesced flush (runs sorted by window)
            int w = wid[j];
            int2 r = rec[j];
            *(long long*)&buf[gdelta[w] + j] = *(long long*)&r;
        }
        __syncthreads();
    }
}

// ---------- fused per-window CSR build: histogram -> LDS scan -> rp -> scatter ----------
__global__ __launch_bounds__(256) void k_build_win(const int2* __restrict__ bufS,
                                                   const int2* __restrict__ bufD,
                                                   const int* __restrict__ baseS,
                                                   const int* __restrict__ baseD,
                                                   int* __restrict__ rpS, int* __restrict__ rpD,
                                                   int* __restrict__ colS, int* __restrict__ colD,
                                                   int Ns, int Nd, int W) {
    __shared__ int h[WNODES];
    __shared__ int sscan[256];
    int b = blockIdx.x, tid = threadIdx.x;
    int dir = (b >= W) ? 1 : 0;
    int w = dir ? b - W : b;
    const int2* buf = dir ? bufD : bufS;
    const int* base = dir ? baseD : baseS;
    int* rp = dir ? rpD : rpS;
    int* col = dir ? colD : colS;
    int N = dir ? Nd : Ns;
    int lo = w << WSH;
    int hi = min(lo + WNODES, N);

    for (int i = tid; i < WNODES; i += 256) h[i] = 0;
    __syncthreads();
    int beg = base[w], end = base[w + 1];
    for (int r = beg + tid; r < end; r += 256)
        atomicAdd(&h[buf[r].x - lo], 1);
    __syncthreads();

    // exclusive scan of h[0..1023] (4 elems/thread + 256-wide LDS scan)
    int i0 = tid * 4;
    int v0 = h[i0], v1 = h[i0 + 1], v2 = h[i0 + 2], v3 = h[i0 + 3];
    int t = v0 + v1 + v2 + v3;
    sscan[tid] = t; __syncthreads();
    for (int off = 1; off < 256; off <<= 1) {
        int x = (tid >= off) ? sscan[tid - off] : 0; __syncthreads();
        sscan[tid] += x; __syncthreads();
    }
    int e0 = sscan[tid] - t;
    int e1 = e0 + v0, e2 = e1 + v1, e3 = e2 + v2;
    h[i0] = e0; h[i0 + 1] = e1; h[i0 + 2] = e2; h[i0 + 3] = e3;  // cursors
    int gi = lo + i0;
    if (gi < hi) rp[gi] = beg + e0;
    if (gi + 1 < hi) rp[gi + 1] = beg + e1;
    if (gi + 2 < hi) rp[gi + 2] = beg + e2;
    if (gi + 3 < hi) rp[gi + 3] = beg + e3;
    if (tid == 255 && hi == N) rp[N] = beg + sscan[255];
    __syncthreads();

    for (int r = beg + tid; r < end; r += 256) {
        int2 rc = buf[r];
        int p = atomicAdd(&h[rc.x - lo], 1);
        col[beg + p] = rc.y;
    }
}

// ---------- feature init: 4 nodes per 256-thread block; dual fp32+fp16 write ----------
__global__ __launch_bounds__(256) void k_init_x(const int* __restrict__ uid, const int* __restrict__ rid,
                         const float* __restrict__ recipe_x,
                         const float* __restrict__ user_emb, const float* __restrict__ recipe_emb,
                         const float* __restrict__ lin_w, const float* __restrict__ lin_b,
                         float* __restrict__ x_user, float* __restrict__ x_recipe,
                         __half* __restrict__ xh_user, __half* __restrict__ xh_recipe,
                         int Nu, int Nr) {
    int n = blockIdx.x * 4 + (threadIdx.x >> 6);
    int h = threadIdx.x & 63;
    if (n < Nr) {
        float o = lin_b[h];
#pragma unroll
        for (int k = 0; k < 10; ++k)   // recipe_x addr wave-uniform -> broadcast load
            o = fmaf(recipe_x[(size_t)n * 10 + k], lin_w[k * H + h], o);
        o += recipe_emb[(size_t)rid[n] * H + h];
        x_recipe[(size_t)n * H + h] = o;
        xh_recipe[(size_t)n * H + h] = __float2half(o);
    }
    if (n < Nu) {
        float o = user_emb[(size_t)uid[n] * H + h];
        x_user[(size_t)n * H + h] = o;
        xh_user[(size_t)n * H + h] = __float2half(o);
    }
}

// ---------- SAGE layer (dual direction in one launch, fp16 gather payload) ----------
// R5 closed the latency question (occupancy +11% at flat dur): the dispatch is
// pinned at ~3.55 TB/s of memory-system bytes. R7 lever: halve gather bytes.
// Gather rows are fp16 (128B row, uint2/lane), accumulated with v_pk_add_f16;
// partials combined and meaned in fp32. Layer-0 outputs stored ONLY as fp16
// (yh): layer 1 gathers them AND reads its root term from them (DSTH=true),
// converting to fp32 in-register; all epilogue math fp32. Layer-1 outputs are
// fp32 (classifier input). Workspace: xh+yh overlay the dead bin buffers ->
// footprint identical to the R5 kernel (R6's +103MB net growth caused a ws
// overflow abort).
template <bool RELU, bool DSTH>
__global__ __launch_bounds__(256, 8) void k_sage2(
    const __half* __restrict__ xhA, const void* __restrict__ xdA,
    const int* __restrict__ rpA, const int* __restrict__ colA,
    const float* __restrict__ WlA, const float* __restrict__ blA,
    const float* __restrict__ WrA, float* __restrict__ outA,
    __half* __restrict__ outhA, int ndA, int nbA,
    const __half* __restrict__ xhB, const void* __restrict__ xdB,
    const int* __restrict__ rpB, const int* __restrict__ colB,
    const float* __restrict__ WlB, const float* __restrict__ blB,
    const float* __restrict__ WrB, float* __restrict__ outB,
    __half* __restrict__ outhB, int ndB) {
    const __half* xh; const void* x_dst; const int* rp; const int* col;
    const float* Wl; const float* bl; const float* Wr; float* out; __half* outh;
    int n_dst, bid;
    if (blockIdx.x < (unsigned)nbA) {
        xh = xhA; x_dst = xdA; rp = rpA; col = colA;
        Wl = WlA; bl = blA; Wr = WrA; out = outA; outh = outhA; n_dst = ndA; bid = blockIdx.x;
    } else {
        xh = xhB; x_dst = xdB; rp = rpB; col = colB;
        Wl = WlB; bl = blB; Wr = WrB; out = outB; outh = outhB; n_dst = ndB; bid = blockIdx.x - nbA;
    }

    int wave = threadIdx.x >> 6, lane = threadIdx.x & 63;
    int c = lane & 15, g = lane >> 4;          // group g owns node n0+g
    int n0 = (bid * 4 + wave) * 4;
    __shared__ float sm[4][4][H];   // [wave][node][feature] mean   (wave-private)
    __shared__ float sx[4][4][H];   // [wave][node][feature] x_dst  (wave-private)

    int n = n0 + g;
    if (n < n_dst) {
        const uint2* xs = (const uint2*)xh;    // fp16 row = 128B = 16 x uint2
        // x_dst row: issued first, overlaps rp/col/gather latency
        float4 xd;
        if (DSTH) {
            uint2 u = ((const uint2*)x_dst)[(n << 4) + c];
            float2 a = __half22float2(*(const __half2*)&u.x);
            float2 b = __half22float2(*(const __half2*)&u.y);
            xd = make_float4(a.x, a.y, b.x, b.y);
        } else {
            xd = ((const float4*)x_dst)[(n << 4) + c];
        }
        int beg = rp[n], end = rp[n + 1];
        __half2 z = __float2half2_rn(0.f);
        __half2 l0 = z, l1 = z, l2 = z, l3 = z;   // lo pair (features 4c, 4c+1)
        __half2 h0 = z, h1 = z, h2 = z, h3 = z;   // hi pair (features 4c+2, 4c+3)
        int e = beg;
        for (; e + 7 < end; e += 8) {           // 8 loads in flight per group
            int r0 = col[e];
            int r1 = col[e + 1];
            int r2 = col[e + 2];
            int r3 = col[e + 3];
            int r4 = col[e + 4];
            int r5 = col[e + 5];
            int r6 = col[e + 6];
            int r7 = col[e + 7];
            uint2 u0 = xs[(r0 << 4) + c];
            uint2 u1 = xs[(r1 << 4) + c];
            uint2 u2 = xs[(r2 << 4) + c];
            uint2 u3 = xs[(r3 << 4) + c];
            uint2 u4 = xs[(r4 << 4) + c];
            uint2 u5 = xs[(r5 << 4) + c];
            uint2 u6 = xs[(r6 << 4) + c];
            uint2 u7 = xs[(r7 << 4) + c];
            l0 = __hadd2(l0, *(const __half2*)&u0.x); h0 = __hadd2(h0, *(const __half2*)&u0.y);
            l1 = __hadd2(l1, *(const __half2*)&u1.x); h1 = __hadd2(h1, *(const __half2*)&u1.y);
            l2 = __hadd2(l2, *(const __half2*)&u2.x); h2 = __hadd2(h2, *(const __half2*)&u2.y);
            l3 = __hadd2(l3, *(const __half2*)&u3.x); h3 = __hadd2(h3, *(const __half2*)&u3.y);
            l0 = __hadd2(l0, *(const __half2*)&u4.x); h0 = __hadd2(h0, *(const __half2*)&u4.y);
            l1 = __hadd2(l1, *(const __half2*)&u5.x); h1 = __hadd2(h1, *(const __half2*)&u5.y);
            l2 = __hadd2(l2, *(const __half2*)&u6.x); h2 = __hadd2(h2, *(const __half2*)&u6.y);
            l3 = __hadd2(l3, *(const __half2*)&u7.x); h3 = __hadd2(h3, *(const __half2*)&u7.y);
        }
        for (; e + 3 < end; e += 4) {
            int r0 = col[e];
            int r1 = col[e + 1];
            int r2 = col[e + 2];
            int r3 = col[e + 3];
            uint2 u0 = xs[(r0 << 4) + c];
            uint2 u1 = xs[(r1 << 4) + c];
            uint2 u2 = xs[(r2 << 4) + c];
            uint2 u3 = xs[(r3 << 4) + c];
            l0 = __hadd2(l0, *(const __half2*)&u0.x); h0 = __hadd2(h0, *(const __half2*)&u0.y);
            l1 = __hadd2(l1, *(const __half2*)&u1.x); h1 = __hadd2(h1, *(const __half2*)&u1.y);
            l2 = __hadd2(l2, *(const __half2*)&u2.x); h2 = __hadd2(h2, *(const __half2*)&u2.y);
            l3 = __hadd2(l3, *(const __half2*)&u3.x); h3 = __hadd2(h3, *(const __half2*)&u3.y);
        }
        for (; e < end; ++e) {
            int r = col[e];
            uint2 u = xs[(r << 4) + c];
            l0 = __hadd2(l0, *(const __half2*)&u.x);
            h0 = __hadd2(h0, *(const __half2*)&u.y);
        }
        // combine the 4 fp16 partial streams in fp32
        float2 fl0 = __half22float2(l0), fl1 = __half22float2(l1);
        float2 fl2 = __half22float2(l2), fl3 = __half22float2(l3);
        float2 fh0 = __half22float2(h0), fh1 = __half22float2(h1);
        float2 fh2 = __half22float2(h2), fh3 = __half22float2(h3);
        float inv = 1.0f / fmaxf((float)(end - beg), 1.0f);
        float4 mv;
        mv.x = ((fl0.x + fl1.x) + (fl2.x + fl3.x)) * inv;
        mv.y = ((fl0.y + fl1.y) + (fl2.y + fl3.y)) * inv;
        mv.z = ((fh0.x + fh1.x) + (fh2.x + fh3.x)) * inv;
        mv.w = ((fh0.y + fh1.y) + (fh2.y + fh3.y)) * inv;
        *((float4*)&sm[wave][g][c * 4]) = mv;
        *((float4*)&sx[wave][g][c * 4]) = xd;
    }
    // wave-local LDS handoff: drain DS writes, forbid reordering. No s_barrier.
    asm volatile("s_waitcnt lgkmcnt(0)" ::: "memory");
    __builtin_amdgcn_sched_barrier(0);

    if (n0 < n_dst) {
        float bb = bl[lane];
        float o0 = bb, o1 = bb, o2 = bb, o3 = bb;
        const float* m = &sm[wave][0][0];   // 4 rows of H, contiguous
        const float* x = &sx[wave][0][0];
#pragma unroll 4
        for (int k = 0; k < H; ++k) {
            float wl = Wl[k * H + lane];    // one 256B L1 load serves 4 nodes
            float wr = Wr[k * H + lane];
            o0 = fmaf(m[0 * H + k], wl, o0); o0 = fmaf(x[0 * H + k], wr, o0);
            o1 = fmaf(m[1 * H + k], wl, o1); o1 = fmaf(x[1 * H + k], wr, o1);
            o2 = fmaf(m[2 * H + k], wl, o2); o2 = fmaf(x[2 * H + k], wr, o2);
            o3 = fmaf(m[3 * H + k], wl, o3); o3 = fmaf(x[3 * H + k], wr, o3);
        }
        if (RELU) {
            o0 = fmaxf(o0, 0.f); o1 = fmaxf(o1, 0.f);
            o2 = fmaxf(o2, 0.f); o3 = fmaxf(o3, 0.f);
        }
        if (out) {
            out[(size_t)n0 * H + lane] = o0;
            if (n0 + 1 < n_dst) out[(size_t)(n0 + 1) * H + lane] = o1;
            if (n0 + 2 < n_dst) out[(size_t)(n0 + 2) * H + lane] = o2;
            if (n0 + 3 < n_dst) out[(size_t)(n0 + 3) * H + lane] = o3;
        }
        if (outh) {   // fp16-only layer-0 outputs: next layer's gather + root
            outh[(size_t)n0 * H + lane] = __float2half(o0);
            if (n0 + 1 < n_dst) outh[(size_t)(n0 + 1) * H + lane] = __float2half(o1);
            if (n0 + 2 < n_dst) outh[(size_t)(n0 + 2) * H + lane] = __float2half(o2);
            if (n0 + 3 < n_dst) outh[(size_t)(n0 + 3) * H + lane] = __float2half(o3);
        }
    }
}

// ---------- classifier: 2 edges per 16-lane group (fp32 features) ----------
__global__ __launch_bounds__(256) void k_dot(const float* __restrict__ xu,
                                             const float* __restrict__ xr,
                                             const int* __restrict__ eli,
                                             float* __restrict__ out, int L) {
    long long wv = (blockIdx.x * 256LL + threadIdx.x) >> 6;
    int lane = threadIdx.x & 63;
    int c = lane & 15, g = lane >> 4;
    long long e0 = wv * 8 + (long long)g * 2;
    if (e0 >= L) return;
    bool two = (e0 + 1 < L);
    int a0 = eli[e0];
    int b0 = eli[(long long)L + e0];
    int a1 = two ? eli[e0 + 1] : a0;
    int b1 = two ? eli[(long long)L + e0 + 1] : b0;
    const float4* XU = (const float4*)xu;
    const float4* XR = (const float4*)xr;
    float4 u0 = XU[(a0 << 4) + c];
    float4 r0 = XR[(b0 << 4) + c];
    float4 u1 = XU[(a1 << 4) + c];
    float4 r1 = XR[(b1 << 4) + c];
    float p0 = u0.x * r0.x; p0 = fmaf(u0.y, r0.y, p0); p0 = fmaf(u0.z, r0.z, p0); p0 = fmaf(u0.w, r0.w, p0);
    float p1 = u1.x * r1.x; p1 = fmaf(u1.y, r1.y, p1); p1 = fmaf(u1.z, r1.z, p1); p1 = fmaf(u1.w, r1.w, p1);
#pragma unroll
    for (int off = 1; off < 16; off <<= 1) {
        p0 += __shfl_xor(p0, off);
        p1 += __shfl_xor(p1, off);
    }
    if (c == 0) {
        out[e0] = p0;
        if (two) out[e0 + 1] = p1;
    }
}

extern "C" void kernel_launch(void* const* d_in, const int* in_sizes, int n_in,
                              void* d_out, int out_size, void* d_ws, size_t ws_size,
                              hipStream_t stream) {
    const int*   uid        = (const int*)d_in[0];
    const int*   rid        = (const int*)d_in[1];
    const float* recipe_x   = (const float*)d_in[2];
    const int*   ei         = (const int*)d_in[3];
    const int*   eli        = (const int*)d_in[4];
    const float* user_emb   = (const float*)d_in[5];
    const float* recipe_emb = (const float*)d_in[6];
    const float* lin_w      = (const float*)d_in[7];
    const float* lin_b      = (const float*)d_in[8];
    const float* Wl         = (const float*)d_in[9];
    const float* bl         = (const float*)d_in[10];
    const float* Wr         = (const float*)d_in[11];

    const int Nu = in_sizes[0], Nr = in_sizes[1];
    const int E = in_sizes[3] / 2, L = in_sizes[4] / 2;
    const int nmax = (Nu > Nr) ? Nu : Nr;
    const int W = ((nmax - 1) >> WSH) + 1;   // 196 for N=200000

    char* ws = (char*)d_ws;
    size_t off = 0;
    auto alloc = [&](size_t bytes) -> char* {
        char* p = ws + off;
        off += (bytes + 255) & ~(size_t)255;
        return p;
    };
    float* x_user   = (float*)alloc((size_t)Nu * H * 4);   // init f32 root; layer-1 out
    float* x_recipe = (float*)alloc((size_t)Nr * H * 4);
    // overlay region: bin buffers (dead after k_build_win) share space with the
    // fp16 feature arrays [xh | yh]. Footprint == R5's (R6's net +103MB aborted).
    size_t hbytes = ((size_t)Nu + Nr) * H * 2;            // one fp16 feature set
    size_t bbytes = (size_t)E * 8 * 2;                    // bufS,bufD
    size_t rbytes = 2 * hbytes;                           // xh + yh = 102.4MB
    char* region  = alloc(rbytes > bbytes ? rbytes : bbytes);
    __half* xh_user   = (__half*)region;
    __half* xh_recipe = (__half*)(region + (size_t)Nu * H * 2);
    __half* yh_user   = (__half*)(region + hbytes);
    __half* yh_recipe = (__half*)(region + hbytes + (size_t)Nu * H * 2);
    int2* bufS = (int2*)region;
    int2* bufD = (int2*)(region + (size_t)E * 8);
    int* rp_src  = (int*)alloc((size_t)(Nu + 1) * 4);
    int* rp_dst  = (int*)alloc((size_t)(Nr + 1) * 4);
    int* col_src = (int*)alloc((size_t)E * 4);
    int* col_dst = (int*)alloc((size_t)E * 4);
    int* winS  = (int*)alloc(MAXW * 4);      // winS..winD adjacent: one memset
    int* winD  = (int*)alloc(MAXW * 4);
    int* baseS = (int*)alloc((MAXW + 1) * 4);
    int* baseD = (int*)alloc((MAXW + 1) * 4);
    int* curS  = (int*)alloc(MAXW * 4);
    int* curD  = (int*)alloc(MAXW * 4);
    (void)ws_size; (void)n_in; (void)out_size;

    // zero window counters (ws is poisoned 0xAA)
    hipMemsetAsync(winS, 0, (size_t)2 * MAXW * 4, stream);

    // CSR build: count -> scan -> bin -> fused per-window (deg+scan+scatter)
    k_wincount<<<1024, 256, 0, stream>>>(ei, E, winS, winD);
    k_scan_win<<<1, 256, 0, stream>>>(winS, winD, baseS, baseD, curS, curD);
    k_bin<<<(E + BINCH - 1) / BINCH, 256, 0, stream>>>(ei, E, curS, curD, bufS, bufD);
    k_build_win<<<2 * W, 256, 0, stream>>>(bufS, bufD, baseS, baseD,
                                           rp_src, rp_dst, col_src, col_dst, Nu, Nr, W);

    // initial features (fp32 root copy + fp16 gather copy; bufs dead by now)
    k_init_x<<<(nmax + 3) / 4, 256, 0, stream>>>(uid, rid, recipe_x, user_emb, recipe_emb,
                                                 lin_w, lin_b, x_user, x_recipe,
                                                 xh_user, xh_recipe, Nu, Nr);

    int nbR = (Nr + 15) / 16, nbU = (Nu + 15) / 16;
    // layer 0 (+ReLU): gather fp16 xh, root fp32 x; output fp16 yh only
    k_sage2<true, false><<<nbR + nbU, 256, 0, stream>>>(
        xh_user, x_recipe, rp_dst, col_dst, Wl + 0 * H * H, bl + 0 * H, Wr + 0 * H * H,
        (float*)nullptr, yh_recipe, Nr, nbR,
        xh_recipe, x_user, rp_src, col_src, Wl + 1 * H * H, bl + 1 * H, Wr + 1 * H * H,
        (float*)nullptr, yh_user, Nu);
    // layer 1 (no ReLU): gather fp16 yh, root fp16 yh; output fp32 x (classifier)
    k_sage2<false, true><<<nbR + nbU, 256, 0, stream>>>(
        yh_user, yh_recipe, rp_dst, col_dst, Wl + 2 * H * H, bl + 2 * H, Wr + 2 * H * H,
        x_recipe, (__half*)nullptr, Nr, nbR,
        yh_recipe, yh_user, rp_src, col_src, Wl + 3 * H * H, bl + 3 * H, Wr + 3 * H * H,
        x_user, (__half*)nullptr, Nu);

    // classifier: 32 edges per block
    long long nblk = ((long long)L + 31) / 32;
    k_dot<<<(int)nblk, 256, 0, stream>>>(x_user, x_recipe, eli, (float*)d_out, L);
}

// Round 8
// 950.701 us; speedup vs baseline: 11.8054x; 1.0204x over previous
//
#include <hip/hip_runtime.h>
#include <hip/hip_fp16.h>

#define H 64
#define MAXW 256        // max windows (scan width)
#define WSH 10          // 1024 nodes per window -> W = ceil(200000/1024) = 196 <= MAXW
#define WNODES (1 << WSH)
#define BINCH 4096      // edges per k_bin block
#define BPT (BINCH / 256)

// ---------- window counting (LDS-aggregated; ~200 global atomics/block) ----------
__global__ __launch_bounds__(256) void k_wincount(const int* __restrict__ ei, int E,
                                                  int* __restrict__ winS, int* __restrict__ winD) {
    __shared__ int hs[MAXW], hd[MAXW];
    hs[threadIdx.x] = 0; hd[threadIdx.x] = 0;
    __syncthreads();
    int stride = gridDim.x * 256;
    for (int e = blockIdx.x * 256 + threadIdx.x; e < E; e += stride) {
        atomicAdd(&hs[ei[e] >> WSH], 1);
        atomicAdd(&hd[ei[E + e] >> WSH], 1);
    }
    __syncthreads();
    if (hs[threadIdx.x]) atomicAdd(&winS[threadIdx.x], hs[threadIdx.x]);
    if (hd[threadIdx.x]) atomicAdd(&winD[threadIdx.x], hd[threadIdx.x]);
}

// Single block: exclusive scan of both window-count arrays (MAXW wide, zero-padded).
__global__ void k_scan_win(const int* __restrict__ winS, const int* __restrict__ winD,
                           int* __restrict__ baseS, int* __restrict__ baseD,
                           int* __restrict__ curS, int* __restrict__ curD) {
    __shared__ int s[256];
    int tid = threadIdx.x;
    int v = winS[tid];
    s[tid] = v; __syncthreads();
    for (int off = 1; off < 256; off <<= 1) {
        int t = (tid >= off) ? s[tid - off] : 0; __syncthreads();
        s[tid] += t; __syncthreads();
    }
    int ex = s[tid] - v;
    baseS[tid] = ex; curS[tid] = ex;
    if (tid == 255) baseS[256] = s[255];
    __syncthreads();
    v = winD[tid];
    s[tid] = v; __syncthreads();
    for (int off = 1; off < 256; off <<= 1) {
        int t = (tid >= off) ? s[tid - off] : 0; __syncthreads();
        s[tid] += t; __syncthreads();
    }
    ex = s[tid] - v;
    baseD[tid] = ex; curD[tid] = ex;
    if (tid == 255) baseD[256] = s[255];
}

// ---------- bin: LDS counting-sort of a 4096-edge chunk by window, coalesced flush ----------
__global__ __launch_bounds__(256) void k_bin(const int* __restrict__ ei, int E,
                                             int* __restrict__ gcurS, int* __restrict__ gcurD,
                                             int2* __restrict__ bufS, int2* __restrict__ bufD) {
    __shared__ int hist[MAXW];
    __shared__ int lbase[MAXW];
    __shared__ int lcur[MAXW];
    __shared__ int gdelta[MAXW];
    __shared__ int2 rec[BINCH];
    __shared__ unsigned char wid[BINCH];
    __shared__ int sscan[256];

    int tid = threadIdx.x;
    int e0 = blockIdx.x * BINCH;
    int n = min(BINCH, E - e0);

    for (int dir = 0; dir < 2; ++dir) {
        int* gcur = dir ? gcurD : gcurS;
        int2* buf = dir ? bufD : bufS;
        hist[tid] = 0;
        __syncthreads();
        int kk[BPT], vv[BPT];
#pragma unroll
        for (int j = 0; j < BPT; ++j) {
            int idx = tid + j * 256;
            if (idx < n) {
                int e = e0 + idx;
                int a = ei[e], b = ei[E + e];
                kk[j] = dir ? b : a;
                vv[j] = dir ? a : b;
                atomicAdd(&hist[kk[j] >> WSH], 1);
            }
        }
        __syncthreads();
        {   // exclusive scan of hist
            int hv = hist[tid];
            sscan[tid] = hv; __syncthreads();
            for (int off = 1; off < 256; off <<= 1) {
                int t = (tid >= off) ? sscan[tid - off] : 0; __syncthreads();
                sscan[tid] += t; __syncthreads();
            }
            lbase[tid] = sscan[tid] - hv;
            lcur[tid] = lbase[tid];
        }
        __syncthreads();
#pragma unroll
        for (int j = 0; j < BPT; ++j) {
            int idx = tid + j * 256;
            if (idx < n) {
                int w = kk[j] >> WSH;
                int p = atomicAdd(&lcur[w], 1);
                rec[p] = make_int2(kk[j], vv[j]);
                wid[p] = (unsigned char)w;
            }
        }
        __syncthreads();
        {   // reserve one contiguous global chunk per non-empty window
            int c = hist[tid];
            int g = c ? atomicAdd(&gcur[tid], c) : 0;
            gdelta[tid] = g - lbase[tid];
        }
        __syncthreads();
        for (int j = tid; j < n; j += 256) {   // coalesced flush (runs sorted by window)
            int w = wid[j];
            int2 r = rec[j];
            *(long long*)&buf[gdelta[w] + j] = *(long long*)&r;
        }
        __syncthreads();
    }
}

// ---------- fused per-window CSR build: histogram -> LDS scan -> rp -> scatter ----------
__global__ __launch_bounds__(256) void k_build_win(const int2* __restrict__ bufS,
                                                   const int2* __restrict__ bufD,
                                                   const int* __restrict__ baseS,
                                                   const int* __restrict__ baseD,
                                                   int* __restrict__ rpS, int* __restrict__ rpD,
                                                   int* __restrict__ colS, int* __restrict__ colD,
                                                   int Ns, int Nd, int W) {
    __shared__ int h[WNODES];
    __shared__ int sscan[256];
    int b = blockIdx.x, tid = threadIdx.x;
    int dir = (b >= W) ? 1 : 0;
    int w = dir ? b - W : b;
    const int2* buf = dir ? bufD : bufS;
    const int* base = dir ? baseD : baseS;
    int* rp = dir ? rpD : rpS;
    int* col = dir ? colD : colS;
    int N = dir ? Nd : Ns;
    int lo = w << WSH;
    int hi = min(lo + WNODES, N);

    for (int i = tid; i < WNODES; i += 256) h[i] = 0;
    __syncthreads();
    int beg = base[w], end = base[w + 1];
    for (int r = beg + tid; r < end; r += 256)
        atomicAdd(&h[buf[r].x - lo], 1);
    __syncthreads();

    // exclusive scan of h[0..1023] (4 elems/thread + 256-wide LDS scan)
    int i0 = tid * 4;
    int v0 = h[i0], v1 = h[i0 + 1], v2 = h[i0 + 2], v3 = h[i0 + 3];
    int t = v0 + v1 + v2 + v3;
    sscan[tid] = t; __syncthreads();
    for (int off = 1; off < 256; off <<= 1) {
        int x = (tid >= off) ? sscan[tid - off] : 0; __syncthreads();
        sscan[tid] += x; __syncthreads();
    }
    int e0 = sscan[tid] - t;
    int e1 = e0 + v0, e2 = e1 + v1, e3 = e2 + v2;
    h[i0] = e0; h[i0 + 1] = e1; h[i0 + 2] = e2; h[i0 + 3] = e3;  // cursors
    int gi = lo + i0;
    if (gi < hi) rp[gi] = beg + e0;
    if (gi + 1 < hi) rp[gi + 1] = beg + e1;
    if (gi + 2 < hi) rp[gi + 2] = beg + e2;
    if (gi + 3 < hi) rp[gi + 3] = beg + e3;
    if (tid == 255 && hi == N) rp[N] = beg + sscan[255];
    __syncthreads();

    for (int r = beg + tid; r < end; r += 256) {
        int2 rc = buf[r];
        int p = atomicAdd(&h[rc.x - lo], 1);
        col[beg + p] = rc.y;
    }
}

// ---------- feature init: 4 nodes per 256-thread block; dual fp32+fp16 write ----------
__global__ __launch_bounds__(256) void k_init_x(const int* __restrict__ uid, const int* __restrict__ rid,
                         const float* __restrict__ recipe_x,
                         const float* __restrict__ user_emb, const float* __restrict__ recipe_emb,
                         const float* __restrict__ lin_w, const float* __restrict__ lin_b,
                         float* __restrict__ x_user, float* __restrict__ x_recipe,
                         __half* __restrict__ xh_user, __half* __restrict__ xh_recipe,
                         int Nu, int Nr) {
    int n = blockIdx.x * 4 + (threadIdx.x >> 6);
    int h = threadIdx.x & 63;
    if (n < Nr) {
        float o = lin_b[h];
#pragma unroll
        for (int k = 0; k < 10; ++k)   // recipe_x addr wave-uniform -> broadcast load
            o = fmaf(recipe_x[(size_t)n * 10 + k], lin_w[k * H + h], o);
        o += recipe_emb[(size_t)rid[n] * H + h];
        x_recipe[(size_t)n * H + h] = o;
        xh_recipe[(size_t)n * H + h] = __float2half(o);
    }
    if (n < Nu) {
        float o = user_emb[(size_t)uid[n] * H + h];
        x_user[(size_t)n * H + h] = o;
        xh_user[(size_t)n * H + h] = __float2half(o);
    }
}

// ---------- SAGE layer (dual direction in one launch, fp16 gather payload) ----------
// R7 established: memory time now sits UNDER a ~195us/dispatch execution floor
// (VALU-busy invariant R0..R7). Dominant term: the epilogue issued 1024
// broadcast ds_read_b32 per wave (every lane re-reads all of sm/sx scalar).
// R8: float4 LDS reads -> 256 ds_read_b128 per wave (4x fewer LDS issues).
// CRITICAL: '#pragma unroll 1' on the k-loop. R3/R4's identical-looking
// epilogue used full unroll (16 iters x 16 live float4) -> scratch spill ->
// FETCH/WRITE exploded to ~8GB. Bounded live set (~60 VGPR) + bounds (256,6)
// (cap 84) keeps it in registers. fmaf order identical to R7 (bitwise-same
// numerics). Gather loop unchanged from R7.
template <bool RELU, bool DSTH>
__global__ __launch_bounds__(256, 6) void k_sage2(
    const __half* __restrict__ xhA, const void* __restrict__ xdA,
    const int* __restrict__ rpA, const int* __restrict__ colA,
    const float* __restrict__ WlA, const float* __restrict__ blA,
    const float* __restrict__ WrA, float* __restrict__ outA,
    __half* __restrict__ outhA, int ndA, int nbA,
    const __half* __restrict__ xhB, const void* __restrict__ xdB,
    const int* __restrict__ rpB, const int* __restrict__ colB,
    const float* __restrict__ WlB, const float* __restrict__ blB,
    const float* __restrict__ WrB, float* __restrict__ outB,
    __half* __restrict__ outhB, int ndB) {
    const __half* xh; const void* x_dst; const int* rp; const int* col;
    const float* Wl; const float* bl; const float* Wr; float* out; __half* outh;
    int n_dst, bid;
    if (blockIdx.x < (unsigned)nbA) {
        xh = xhA; x_dst = xdA; rp = rpA; col = colA;
        Wl = WlA; bl = blA; Wr = WrA; out = outA; outh = outhA; n_dst = ndA; bid = blockIdx.x;
    } else {
        xh = xhB; x_dst = xdB; rp = rpB; col = colB;
        Wl = WlB; bl = blB; Wr = WrB; out = outB; outh = outhB; n_dst = ndB; bid = blockIdx.x - nbA;
    }

    int wave = threadIdx.x >> 6, lane = threadIdx.x & 63;
    int c = lane & 15, g = lane >> 4;          // group g owns node n0+g
    int n0 = (bid * 4 + wave) * 4;
    __shared__ __align__(16) float sm[4][4][H];   // [wave][node][feat] mean  (wave-private)
    __shared__ __align__(16) float sx[4][4][H];   // [wave][node][feat] x_dst (wave-private)

    int n = n0 + g;
    if (n < n_dst) {
        const uint2* xs = (const uint2*)xh;    // fp16 row = 128B = 16 x uint2
        // x_dst row: issued first, overlaps rp/col/gather latency
        float4 xd;
        if (DSTH) {
            uint2 u = ((const uint2*)x_dst)[(n << 4) + c];
            float2 a = __half22float2(*(const __half2*)&u.x);
            float2 b = __half22float2(*(const __half2*)&u.y);
            xd = make_float4(a.x, a.y, b.x, b.y);
        } else {
            xd = ((const float4*)x_dst)[(n << 4) + c];
        }
        int beg = rp[n], end = rp[n + 1];
        __half2 z = __float2half2_rn(0.f);
        __half2 l0 = z, l1 = z, l2 = z, l3 = z;   // lo pair (features 4c, 4c+1)
        __half2 h0 = z, h1 = z, h2 = z, h3 = z;   // hi pair (features 4c+2, 4c+3)
        int e = beg;
        for (; e + 7 < end; e += 8) {           // 8 loads in flight per group
            int r0 = col[e];
            int r1 = col[e + 1];
            int r2 = col[e + 2];
            int r3 = col[e + 3];
            int r4 = col[e + 4];
            int r5 = col[e + 5];
            int r6 = col[e + 6];
            int r7 = col[e + 7];
            uint2 u0 = xs[(r0 << 4) + c];
            uint2 u1 = xs[(r1 << 4) + c];
            uint2 u2 = xs[(r2 << 4) + c];
            uint2 u3 = xs[(r3 << 4) + c];
            uint2 u4 = xs[(r4 << 4) + c];
            uint2 u5 = xs[(r5 << 4) + c];
            uint2 u6 = xs[(r6 << 4) + c];
            uint2 u7 = xs[(r7 << 4) + c];
            l0 = __hadd2(l0, *(const __half2*)&u0.x); h0 = __hadd2(h0, *(const __half2*)&u0.y);
            l1 = __hadd2(l1, *(const __half2*)&u1.x); h1 = __hadd2(h1, *(const __half2*)&u1.y);
            l2 = __hadd2(l2, *(const __half2*)&u2.x); h2 = __hadd2(h2, *(const __half2*)&u2.y);
            l3 = __hadd2(l3, *(const __half2*)&u3.x); h3 = __hadd2(h3, *(const __half2*)&u3.y);
            l0 = __hadd2(l0, *(const __half2*)&u4.x); h0 = __hadd2(h0, *(const __half2*)&u4.y);
            l1 = __hadd2(l1, *(const __half2*)&u5.x); h1 = __hadd2(h1, *(const __half2*)&u5.y);
            l2 = __hadd2(l2, *(const __half2*)&u6.x); h2 = __hadd2(h2, *(const __half2*)&u6.y);
            l3 = __hadd2(l3, *(const __half2*)&u7.x); h3 = __hadd2(h3, *(const __half2*)&u7.y);
        }
        for (; e + 3 < end; e += 4) {
            int r0 = col[e];
            int r1 = col[e + 1];
            int r2 = col[e + 2];
            int r3 = col[e + 3];
            uint2 u0 = xs[(r0 << 4) + c];
            uint2 u1 = xs[(r1 << 4) + c];
            uint2 u2 = xs[(r2 << 4) + c];
            uint2 u3 = xs[(r3 << 4) + c];
            l0 = __hadd2(l0, *(const __half2*)&u0.x); h0 = __hadd2(h0, *(const __half2*)&u0.y);
            l1 = __hadd2(l1, *(const __half2*)&u1.x); h1 = __hadd2(h1, *(const __half2*)&u1.y);
            l2 = __hadd2(l2, *(const __half2*)&u2.x); h2 = __hadd2(h2, *(const __half2*)&u2.y);
            l3 = __hadd2(l3, *(const __half2*)&u3.x); h3 = __hadd2(h3, *(const __half2*)&u3.y);
        }
        for (; e < end; ++e) {
            int r = col[e];
            uint2 u = xs[(r << 4) + c];
            l0 = __hadd2(l0, *(const __half2*)&u.x);
            h0 = __hadd2(h0, *(const __half2*)&u.y);
        }
        // combine the 4 fp16 partial streams in fp32
        float2 fl0 = __half22float2(l0), fl1 = __half22float2(l1);
        float2 fl2 = __half22float2(l2), fl3 = __half22float2(l3);
        float2 fh0 = __half22float2(h0), fh1 = __half22float2(h1);
        float2 fh2 = __half22float2(h2), fh3 = __half22float2(h3);
        float inv = 1.0f / fmaxf((float)(end - beg), 1.0f);
        float4 mv;
        mv.x = ((fl0.x + fl1.x) + (fl2.x + fl3.x)) * inv;
        mv.y = ((fl0.y + fl1.y) + (fl2.y + fl3.y)) * inv;
        mv.z = ((fh0.x + fh1.x) + (fh2.x + fh3.x)) * inv;
        mv.w = ((fh0.y + fh1.y) + (fh2.y + fh3.y)) * inv;
        *((float4*)&sm[wave][g][c * 4]) = mv;
        *((float4*)&sx[wave][g][c * 4]) = xd;
    }
    // wave-local LDS handoff: drain DS writes, forbid reordering. No s_barrier.
    asm volatile("s_waitcnt lgkmcnt(0)" ::: "memory");
    __builtin_amdgcn_sched_barrier(0);

    if (n0 < n_dst) {
        float bb = bl[lane];
        float o0 = bb, o1 = bb, o2 = bb, o3 = bb;
        const float* m = &sm[wave][0][0];   // 4 rows of H, contiguous
        const float* x = &sx[wave][0][0];
#pragma unroll 1
        for (int k = 0; k < H; k += 4) {    // 8 ds_read_b128 + 8 L1 loads + 32 fmaf / iter
            float4 m0 = *(const float4*)(m + 0 * H + k);
            float4 m1 = *(const float4*)(m + 1 * H + k);
            float4 m2 = *(const float4*)(m + 2 * H + k);
            float4 m3 = *(const float4*)(m + 3 * H + k);
            float4 x0 = *(const float4*)(x + 0 * H + k);
            float4 x1 = *(const float4*)(x + 1 * H + k);
            float4 x2 = *(const float4*)(x + 2 * H + k);
            float4 x3 = *(const float4*)(x + 3 * H + k);
            float wl0 = Wl[(k + 0) * H + lane], wr0 = Wr[(k + 0) * H + lane];
            float wl1 = Wl[(k + 1) * H + lane], wr1 = Wr[(k + 1) * H + lane];
            float wl2 = Wl[(k + 2) * H + lane], wr2 = Wr[(k + 2) * H + lane];
            float wl3 = Wl[(k + 3) * H + lane], wr3 = Wr[(k + 3) * H + lane];
            o0 = fmaf(m0.x, wl0, o0); o0 = fmaf(x0.x, wr0, o0);
            o1 = fmaf(m1.x, wl0, o1); o1 = fmaf(x1.x, wr0, o1);
            o2 = fmaf(m2.x, wl0, o2); o2 = fmaf(x2.x, wr0, o2);
            o3 = fmaf(m3.x, wl0, o3); o3 = fmaf(x3.x, wr0, o3);
            o0 = fmaf(m0.y, wl1, o0); o0 = fmaf(x0.y, wr1, o0);
            o1 = fmaf(m1.y, wl1, o1); o1 = fmaf(x1.y, wr1, o1);
            o2 = fmaf(m2.y, wl1, o2); o2 = fmaf(x2.y, wr1, o2);
            o3 = fmaf(m3.y, wl1, o3); o3 = fmaf(x3.y, wr1, o3);
            o0 = fmaf(m0.z, wl2, o0); o0 = fmaf(x0.z, wr2, o0);
            o1 = fmaf(m1.z, wl2, o1); o1 = fmaf(x1.z, wr2, o1);
            o2 = fmaf(m2.z, wl2, o2); o2 = fmaf(x2.z, wr2, o2);
            o3 = fmaf(m3.z, wl2, o3); o3 = fmaf(x3.z, wr2, o3);
            o0 = fmaf(m0.w, wl3, o0); o0 = fmaf(x0.w, wr3, o0);
            o1 = fmaf(m1.w, wl3, o1); o1 = fmaf(x1.w, wr3, o1);
            o2 = fmaf(m2.w, wl3, o2); o2 = fmaf(x2.w, wr3, o2);
            o3 = fmaf(m3.w, wl3, o3); o3 = fmaf(x3.w, wr3, o3);
        }
        if (RELU) {
            o0 = fmaxf(o0, 0.f); o1 = fmaxf(o1, 0.f);
            o2 = fmaxf(o2, 0.f); o3 = fmaxf(o3, 0.f);
        }
        if (out) {
            out[(size_t)n0 * H + lane] = o0;
            if (n0 + 1 < n_dst) out[(size_t)(n0 + 1) * H + lane] = o1;
            if (n0 + 2 < n_dst) out[(size_t)(n0 + 2) * H + lane] = o2;
            if (n0 + 3 < n_dst) out[(size_t)(n0 + 3) * H + lane] = o3;
        }
        if (outh) {   // fp16-only layer-0 outputs: next layer's gather + root
            outh[(size_t)n0 * H + lane] = __float2half(o0);
            if (n0 + 1 < n_dst) outh[(size_t)(n0 + 1) * H + lane] = __float2half(o1);
            if (n0 + 2 < n_dst) outh[(size_t)(n0 + 2) * H + lane] = __float2half(o2);
            if (n0 + 3 < n_dst) outh[(size_t)(n0 + 3) * H + lane] = __float2half(o3);
        }
    }
}

// ---------- classifier: 2 edges per 16-lane group (fp32 features) ----------
__global__ __launch_bounds__(256) void k_dot(const float* __restrict__ xu,
                                             const float* __restrict__ xr,
                                             const int* __restrict__ eli,
                                             float* __restrict__ out, int L) {
    long long wv = (blockIdx.x * 256LL + threadIdx.x) >> 6;
    int lane = threadIdx.x & 63;
    int c = lane & 15, g = lane >> 4;
    long long e0 = wv * 8 + (long long)g * 2;
    if (e0 >= L) return;
    bool two = (e0 + 1 < L);
    int a0 = eli[e0];
    int b0 = eli[(long long)L + e0];
    int a1 = two ? eli[e0 + 1] : a0;
    int b1 = two ? eli[(long long)L + e0 + 1] : b0;
    const float4* XU = (const float4*)xu;
    const float4* XR = (const float4*)xr;
    float4 u0 = XU[(a0 << 4) + c];
    float4 r0 = XR[(b0 << 4) + c];
    float4 u1 = XU[(a1 << 4) + c];
    float4 r1 = XR[(b1 << 4) + c];
    float p0 = u0.x * r0.x; p0 = fmaf(u0.y, r0.y, p0); p0 = fmaf(u0.z, r0.z, p0); p0 = fmaf(u0.w, r0.w, p0);
    float p1 = u1.x * r1.x; p1 = fmaf(u1.y, r1.y, p1); p1 = fmaf(u1.z, r1.z, p1); p1 = fmaf(u1.w, r1.w, p1);
#pragma unroll
    for (int off = 1; off < 16; off <<= 1) {
        p0 += __shfl_xor(p0, off);
        p1 += __shfl_xor(p1, off);
    }
    if (c == 0) {
        out[e0] = p0;
        if (two) out[e0 + 1] = p1;
    }
}

extern "C" void kernel_launch(void* const* d_in, const int* in_sizes, int n_in,
                              void* d_out, int out_size, void* d_ws, size_t ws_size,
                              hipStream_t stream) {
    const int*   uid        = (const int*)d_in[0];
    const int*   rid        = (const int*)d_in[1];
    const float* recipe_x   = (const float*)d_in[2];
    const int*   ei         = (const int*)d_in[3];
    const int*   eli        = (const int*)d_in[4];
    const float* user_emb   = (const float*)d_in[5];
    const float* recipe_emb = (const float*)d_in[6];
    const float* lin_w      = (const float*)d_in[7];
    const float* lin_b      = (const float*)d_in[8];
    const float* Wl         = (const float*)d_in[9];
    const float* bl         = (const float*)d_in[10];
    const float* Wr         = (const float*)d_in[11];

    const int Nu = in_sizes[0], Nr = in_sizes[1];
    const int E = in_sizes[3] / 2, L = in_sizes[4] / 2;
    const int nmax = (Nu > Nr) ? Nu : Nr;
    const int W = ((nmax - 1) >> WSH) + 1;   // 196 for N=200000

    char* ws = (char*)d_ws;
    size_t off = 0;
    auto alloc = [&](size_t bytes) -> char* {
        char* p = ws + off;
        off += (bytes + 255) & ~(size_t)255;
        return p;
    };
    float* x_user   = (float*)alloc((size_t)Nu * H * 4);   // init f32 root; layer-1 out
    float* x_recipe = (float*)alloc((size_t)Nr * H * 4);
    // overlay region: bin buffers (dead after k_build_win) share space with the
    // fp16 feature arrays [xh | yh]. Footprint == R5's (R6's net +103MB aborted).
    size_t hbytes = ((size_t)Nu + Nr) * H * 2;            // one fp16 feature set
    size_t bbytes = (size_t)E * 8 * 2;                    // bufS,bufD
    size_t rbytes = 2 * hbytes;                           // xh + yh = 102.4MB
    char* region  = alloc(rbytes > bbytes ? rbytes : bbytes);
    __half* xh_user   = (__half*)region;
    __half* xh_recipe = (__half*)(region + (size_t)Nu * H * 2);
    __half* yh_user   = (__half*)(region + hbytes);
    __half* yh_recipe = (__half*)(region + hbytes + (size_t)Nu * H * 2);
    int2* bufS = (int2*)region;
    int2* bufD = (int2*)(region + (size_t)E * 8);
    int* rp_src  = (int*)alloc((size_t)(Nu + 1) * 4);
    int* rp_dst  = (int*)alloc((size_t)(Nr + 1) * 4);
    int* col_src = (int*)alloc((size_t)E * 4);
    int* col_dst = (int*)alloc((size_t)E * 4);
    int* winS  = (int*)alloc(MAXW * 4);      // winS..winD adjacent: one memset
    int* winD  = (int*)alloc(MAXW * 4);
    int* baseS = (int*)alloc((MAXW + 1) * 4);
    int* baseD = (int*)alloc((MAXW + 1) * 4);
    int* curS  = (int*)alloc(MAXW * 4);
    int* curD  = (int*)alloc(MAXW * 4);
    (void)ws_size; (void)n_in; (void)out_size;

    // zero window counters (ws is poisoned 0xAA)
    hipMemsetAsync(winS, 0, (size_t)2 * MAXW * 4, stream);

    // CSR build: count -> scan -> bin -> fused per-window (deg+scan+scatter)
    k_wincount<<<1024, 256, 0, stream>>>(ei, E, winS, winD);
    k_scan_win<<<1, 256, 0, stream>>>(winS, winD, baseS, baseD, curS, curD);
    k_bin<<<(E + BINCH - 1) / BINCH, 256, 0, stream>>>(ei, E, curS, curD, bufS, bufD);
    k_build_win<<<2 * W, 256, 0, stream>>>(bufS, bufD, baseS, baseD,
                                           rp_src, rp_dst, col_src, col_dst, Nu, Nr, W);

    // initial features (fp32 root copy + fp16 gather copy; bufs dead by now)
    k_init_x<<<(nmax + 3) / 4, 256, 0, stream>>>(uid, rid, recipe_x, user_emb, recipe_emb,
                                                 lin_w, lin_b, x_user, x_recipe,
                                                 xh_user, xh_recipe, Nu, Nr);

    int nbR = (Nr + 15) / 16, nbU = (Nu + 15) / 16;
    // layer 0 (+ReLU): gather fp16 xh, root fp32 x; output fp16 yh only
    k_sage2<true, false><<<nbR + nbU, 256, 0, stream>>>(
        xh_user, x_recipe, rp_dst, col_dst, Wl + 0 * H * H, bl + 0 * H, Wr + 0 * H * H,
        (float*)nullptr, yh_recipe, Nr, nbR,
        xh_recipe, x_user, rp_src, col_src, Wl + 1 * H * H, bl + 1 * H, Wr + 1 * H * H,
        (float*)nullptr, yh_user, Nu);
    // layer 1 (no ReLU): gather fp16 yh, root fp16 yh; output fp32 x (classifier)
    k_sage2<false, true><<<nbR + nbU, 256, 0, stream>>>(
        yh_user, yh_recipe, rp_dst, col_dst, Wl + 2 * H * H, bl + 2 * H, Wr + 2 * H * H,
        x_recipe, (__half*)nullptr, Nr, nbR,
        yh_recipe, yh_user, rp_src, col_src, Wl + 3 * H * H, bl + 3 * H, Wr + 3 * H * H,
        x_user, (__half*)nullptr, Nu);

    // classifier: 32 edges per block
    long long nblk = ((long long)L + 31) / 32;
    k_dot<<<(int)nblk, 256, 0, stream>>>(x_user, x_recipe, eli, (float*)d_out, L);
}

// Round 9
// 782.971 us; speedup vs baseline: 14.3343x; 1.2142x over previous
//
#include <hip/hip_runtime.h>
#include <hip/hip_fp16.h>

#define H 64
#define MAXW 256        // max windows (scan width)
#define WSH 10          // 1024 nodes per window -> W = ceil(200000/1024) = 196 <= MAXW
#define WNODES (1 << WSH)
#define BINCH 4096      // edges per k_bin block
#define BPT (BINCH / 256)

typedef _Float16 half4_t __attribute__((ext_vector_type(4)));
typedef float floatx4 __attribute__((ext_vector_type(4)));

// ---------- window counting (LDS-aggregated; ~200 global atomics/block) ----------
__global__ __launch_bounds__(256) void k_wincount(const int* __restrict__ ei, int E,
                                                  int* __restrict__ winS, int* __restrict__ winD) {
    __shared__ int hs[MAXW], hd[MAXW];
    hs[threadIdx.x] = 0; hd[threadIdx.x] = 0;
    __syncthreads();
    int stride = gridDim.x * 256;
    for (int e = blockIdx.x * 256 + threadIdx.x; e < E; e += stride) {
        atomicAdd(&hs[ei[e] >> WSH], 1);
        atomicAdd(&hd[ei[E + e] >> WSH], 1);
    }
    __syncthreads();
    if (hs[threadIdx.x]) atomicAdd(&winS[threadIdx.x], hs[threadIdx.x]);
    if (hd[threadIdx.x]) atomicAdd(&winD[threadIdx.x], hd[threadIdx.x]);
}

// Single block: exclusive scan of both window-count arrays (MAXW wide, zero-padded).
__global__ void k_scan_win(const int* __restrict__ winS, const int* __restrict__ winD,
                           int* __restrict__ baseS, int* __restrict__ baseD,
                           int* __restrict__ curS, int* __restrict__ curD) {
    __shared__ int s[256];
    int tid = threadIdx.x;
    int v = winS[tid];
    s[tid] = v; __syncthreads();
    for (int off = 1; off < 256; off <<= 1) {
        int t = (tid >= off) ? s[tid - off] : 0; __syncthreads();
        s[tid] += t; __syncthreads();
    }
    int ex = s[tid] - v;
    baseS[tid] = ex; curS[tid] = ex;
    if (tid == 255) baseS[256] = s[255];
    __syncthreads();
    v = winD[tid];
    s[tid] = v; __syncthreads();
    for (int off = 1; off < 256; off <<= 1) {
        int t = (tid >= off) ? s[tid - off] : 0; __syncthreads();
        s[tid] += t; __syncthreads();
    }
    ex = s[tid] - v;
    baseD[tid] = ex; curD[tid] = ex;
    if (tid == 255) baseD[256] = s[255];
}

// ---------- bin: LDS counting-sort of a 4096-edge chunk by window, coalesced flush ----------
__global__ __launch_bounds__(256) void k_bin(const int* __restrict__ ei, int E,
                                             int* __restrict__ gcurS, int* __restrict__ gcurD,
                                             int2* __restrict__ bufS, int2* __restrict__ bufD) {
    __shared__ int hist[MAXW];
    __shared__ int lbase[MAXW];
    __shared__ int lcur[MAXW];
    __shared__ int gdelta[MAXW];
    __shared__ int2 rec[BINCH];
    __shared__ unsigned char wid[BINCH];
    __shared__ int sscan[256];

    int tid = threadIdx.x;
    int e0 = blockIdx.x * BINCH;
    int n = min(BINCH, E - e0);

    for (int dir = 0; dir < 2; ++dir) {
        int* gcur = dir ? gcurD : gcurS;
        int2* buf = dir ? bufD : bufS;
        hist[tid] = 0;
        __syncthreads();
        int kk[BPT], vv[BPT];
#pragma unroll
        for (int j = 0; j < BPT; ++j) {
            int idx = tid + j * 256;
            if (idx < n) {
                int e = e0 + idx;
                int a = ei[e], b = ei[E + e];
                kk[j] = dir ? b : a;
                vv[j] = dir ? a : b;
                atomicAdd(&hist[kk[j] >> WSH], 1);
            }
        }
        __syncthreads();
        {   // exclusive scan of hist
            int hv = hist[tid];
            sscan[tid] = hv; __syncthreads();
            for (int off = 1; off < 256; off <<= 1) {
                int t = (tid >= off) ? sscan[tid - off] : 0; __syncthreads();
                sscan[tid] += t; __syncthreads();
            }
            lbase[tid] = sscan[tid] - hv;
            lcur[tid] = lbase[tid];
        }
        __syncthreads();
#pragma unroll
        for (int j = 0; j < BPT; ++j) {
            int idx = tid + j * 256;
            if (idx < n) {
                int w = kk[j] >> WSH;
                int p = atomicAdd(&lcur[w], 1);
                rec[p] = make_int2(kk[j], vv[j]);
                wid[p] = (unsigned char)w;
            }
        }
        __syncthreads();
        {   // reserve one contiguous global chunk per non-empty window
            int c = hist[tid];
            int g = c ? atomicAdd(&gcur[tid], c) : 0;
            gdelta[tid] = g - lbase[tid];
        }
        __syncthreads();
        for (int j = tid; j < n; j += 256) {   // coalesced flush (runs sorted by window)
            int w = wid[j];
            int2 r = rec[j];
            *(long long*)&buf[gdelta[w] + j] = *(long long*)&r;
        }
        __syncthreads();
    }
}

// ---------- fused per-window CSR build: histogram -> LDS scan -> rp -> scatter ----------
__global__ __launch_bounds__(256) void k_build_win(const int2* __restrict__ bufS,
                                                   const int2* __restrict__ bufD,
                                                   const int* __restrict__ baseS,
                                                   const int* __restrict__ baseD,
                                                   int* __restrict__ rpS, int* __restrict__ rpD,
                                                   int* __restrict__ colS, int* __restrict__ colD,
                                                   int Ns, int Nd, int W) {
    __shared__ int h[WNODES];
    __shared__ int sscan[256];
    int b = blockIdx.x, tid = threadIdx.x;
    int dir = (b >= W) ? 1 : 0;
    int w = dir ? b - W : b;
    const int2* buf = dir ? bufD : bufS;
    const int* base = dir ? baseD : baseS;
    int* rp = dir ? rpD : rpS;
    int* col = dir ? colD : colS;
    int N = dir ? Nd : Ns;
    int lo = w << WSH;
    int hi = min(lo + WNODES, N);

    for (int i = tid; i < WNODES; i += 256) h[i] = 0;
    __syncthreads();
    int beg = base[w], end = base[w + 1];
    for (int r = beg + tid; r < end; r += 256)
        atomicAdd(&h[buf[r].x - lo], 1);
    __syncthreads();

    // exclusive scan of h[0..1023] (4 elems/thread + 256-wide LDS scan)
    int i0 = tid * 4;
    int v0 = h[i0], v1 = h[i0 + 1], v2 = h[i0 + 2], v3 = h[i0 + 3];
    int t = v0 + v1 + v2 + v3;
    sscan[tid] = t; __syncthreads();
    for (int off = 1; off < 256; off <<= 1) {
        int x = (tid >= off) ? sscan[tid - off] : 0; __syncthreads();
        sscan[tid] += x; __syncthreads();
    }
    int e0 = sscan[tid] - t;
    int e1 = e0 + v0, e2 = e1 + v1, e3 = e2 + v2;
    h[i0] = e0; h[i0 + 1] = e1; h[i0 + 2] = e2; h[i0 + 3] = e3;  // cursors
    int gi = lo + i0;
    if (gi < hi) rp[gi] = beg + e0;
    if (gi + 1 < hi) rp[gi + 1] = beg + e1;
    if (gi + 2 < hi) rp[gi + 2] = beg + e2;
    if (gi + 3 < hi) rp[gi + 3] = beg + e3;
    if (tid == 255 && hi == N) rp[N] = beg + sscan[255];
    __syncthreads();

    for (int r = beg + tid; r < end; r += 256) {
        int2 rc = buf[r];
        int p = atomicAdd(&h[rc.x - lo], 1);
        col[beg + p] = rc.y;
    }
}

// ---------- weight prep: fp32 [layer][rel][64][64] -> fp16 MFMA-fragment order ----------
// Out per matrix: idx = ((ks*4 + g4)*64 + col)*4 + j holds W[k=ks*16+g4*4+j][col],
// so lane (k-group g4, col) reads its 4 B-elements as one contiguous 8B load.
// 8 matrices: m = layer*4 + rel*2 + lr (lr: 0=Wl, 1=Wr).
__global__ __launch_bounds__(256) void k_prep_w(const float* __restrict__ Wl,
                                                const float* __restrict__ Wr,
                                                _Float16* __restrict__ w16) {
    int gid = blockIdx.x * 256 + threadIdx.x;     // 8 * 4096 = 32768
    int m = gid >> 12;
    int o = gid & 4095;
    int ks = o >> 10, g4 = (o >> 8) & 3, col = (o >> 2) & 63, j = o & 3;
    int k = (ks << 4) + (g4 << 2) + j;
    int lr = m & 1, rel = (m >> 1) & 1, layer = m >> 2;
    const float* Wsrc = lr ? Wr : Wl;
    w16[gid] = (_Float16)Wsrc[((layer * 2 + rel) * 64 + k) * 64 + col];
}

// ---------- feature init: fp16-only features (fp32 path deleted) ----------
__global__ __launch_bounds__(256) void k_init_x(const int* __restrict__ uid, const int* __restrict__ rid,
                         const float* __restrict__ recipe_x,
                         const float* __restrict__ user_emb, const float* __restrict__ recipe_emb,
                         const float* __restrict__ lin_w, const float* __restrict__ lin_b,
                         __half* __restrict__ xh_user, __half* __restrict__ xh_recipe,
                         int Nu, int Nr) {
    int n = blockIdx.x * 4 + (threadIdx.x >> 6);
    int h = threadIdx.x & 63;
    if (n < Nr) {
        float o = lin_b[h];
#pragma unroll
        for (int k = 0; k < 10; ++k)   // recipe_x addr wave-uniform -> broadcast load
            o = fmaf(recipe_x[(size_t)n * 10 + k], lin_w[k * H + h], o);
        o += recipe_emb[(size_t)rid[n] * H + h];
        xh_recipe[(size_t)n * H + h] = __float2half(o);
    }
    if (n < Nu) {
        xh_user[(size_t)n * H + h] = __float2half(user_emb[(size_t)uid[n] * H + h]);
    }
}

// ---------- SAGE layer: fp16 gather + MFMA epilogue ----------
// R8 closed the loop-structure question: the ~186us/dispatch floor is VALU
// issue, dominated by the epilogue's 512 fmaf/lane (2x H*H matmul for 4
// nodes). R9 moves it to the matrix pipe: per block, Y[16x64] =
// M[16x64]@Wl + X[16x64]@Wr + bl via v_mfma_f32_16x16x16_f16. Each wave owns
// one 16-col N-tile: 8 MFMAs replace 512 fmaf (fp32 accumulate).
// Fragment layouts (classic K=16 shape; C/D = m89-verified mapping):
//   A: row=lane%16 (node), k=ks*16 + 4*(lane/16)+j  -> 8B LDS read, stride-72
//      rows => <=2-way bank alias (free per m136)
//   B: col=lane%16, same k                          -> 8B load from k_prep_w
//   D: col=lane&15, row=(lane>>4)*4+reg (node)
// Gather loop unchanged from R8. sm/sx now block-shared fp16 [16][72]; one
// __syncthreads (waves cooperate). All features fp16 end-to-end (layer-1 out
// + classifier input); fp32 x arrays deleted (ws ~136MB, R6 lesson).
template <bool RELU>
__global__ __launch_bounds__(256, 6) void k_sage3(
    const __half* __restrict__ gsA, const __half* __restrict__ rtA,
    const int* __restrict__ rpA, const int* __restrict__ colA,
    const _Float16* __restrict__ wlA, const _Float16* __restrict__ wrA,
    const float* __restrict__ blA, __half* __restrict__ outA, int ndA, int nbA,
    const __half* __restrict__ gsB, const __half* __restrict__ rtB,
    const int* __restrict__ rpB, const int* __restrict__ colB,
    const _Float16* __restrict__ wlB, const _Float16* __restrict__ wrB,
    const float* __restrict__ blB, __half* __restrict__ outB, int ndB) {
    const __half* gs; const __half* rt; const int* rp; const int* col;
    const _Float16* wl16; const _Float16* wr16; const float* bl; __half* outh;
    int n_dst, bid;
    if (blockIdx.x < (unsigned)nbA) {
        gs = gsA; rt = rtA; rp = rpA; col = colA;
        wl16 = wlA; wr16 = wrA; bl = blA; outh = outA; n_dst = ndA; bid = blockIdx.x;
    } else {
        gs = gsB; rt = rtB; rp = rpB; col = colB;
        wl16 = wlB; wr16 = wrB; bl = blB; outh = outB; n_dst = ndB; bid = blockIdx.x - nbA;
    }

    int wave = threadIdx.x >> 6, lane = threadIdx.x & 63;
    int c = lane & 15, g = lane >> 4;          // group g owns node local=wave*4+g
    __shared__ __align__(16) _Float16 smh[16][72];   // [node][feat] mean, stride 72
    __shared__ __align__(16) _Float16 sxh[16][72];   // [node][feat] root

    int local = (wave << 2) + g;
    int n = bid * 16 + local;
    if (n < n_dst) {
        const uint2* xs = (const uint2*)gs;    // fp16 row = 128B = 16 x uint2
        uint2 xdu = ((const uint2*)rt)[(n << 4) + c];   // root row, overlaps gather
        int beg = rp[n], end = rp[n + 1];
        __half2 z = __float2half2_rn(0.f);
        __half2 l0 = z, l1 = z, l2 = z, l3 = z;   // lo pair (features 4c, 4c+1)
        __half2 h0 = z, h1 = z, h2 = z, h3 = z;   // hi pair (features 4c+2, 4c+3)
        int e = beg;
        for (; e + 7 < end; e += 8) {           // 8 loads in flight per group
            int r0 = col[e];
            int r1 = col[e + 1];
            int r2 = col[e + 2];
            int r3 = col[e + 3];
            int r4 = col[e + 4];
            int r5 = col[e + 5];
            int r6 = col[e + 6];
            int r7 = col[e + 7];
            uint2 u0 = xs[(r0 << 4) + c];
            uint2 u1 = xs[(r1 << 4) + c];
            uint2 u2 = xs[(r2 << 4) + c];
            uint2 u3 = xs[(r3 << 4) + c];
            uint2 u4 = xs[(r4 << 4) + c];
            uint2 u5 = xs[(r5 << 4) + c];
            uint2 u6 = xs[(r6 << 4) + c];
            uint2 u7 = xs[(r7 << 4) + c];
            l0 = __hadd2(l0, *(const __half2*)&u0.x); h0 = __hadd2(h0, *(const __half2*)&u0.y);
            l1 = __hadd2(l1, *(const __half2*)&u1.x); h1 = __hadd2(h1, *(const __half2*)&u1.y);
            l2 = __hadd2(l2, *(const __half2*)&u2.x); h2 = __hadd2(h2, *(const __half2*)&u2.y);
            l3 = __hadd2(l3, *(const __half2*)&u3.x); h3 = __hadd2(h3, *(const __half2*)&u3.y);
            l0 = __hadd2(l0, *(const __half2*)&u4.x); h0 = __hadd2(h0, *(const __half2*)&u4.y);
            l1 = __hadd2(l1, *(const __half2*)&u5.x); h1 = __hadd2(h1, *(const __half2*)&u5.y);
            l2 = __hadd2(l2, *(const __half2*)&u6.x); h2 = __hadd2(h2, *(const __half2*)&u6.y);
            l3 = __hadd2(l3, *(const __half2*)&u7.x); h3 = __hadd2(h3, *(const __half2*)&u7.y);
        }
        for (; e + 3 < end; e += 4) {
            int r0 = col[e];
            int r1 = col[e + 1];
            int r2 = col[e + 2];
            int r3 = col[e + 3];
            uint2 u0 = xs[(r0 << 4) + c];
            uint2 u1 = xs[(r1 << 4) + c];
            uint2 u2 = xs[(r2 << 4) + c];
            uint2 u3 = xs[(r3 << 4) + c];
            l0 = __hadd2(l0, *(const __half2*)&u0.x); h0 = __hadd2(h0, *(const __half2*)&u0.y);
            l1 = __hadd2(l1, *(const __half2*)&u1.x); h1 = __hadd2(h1, *(const __half2*)&u1.y);
            l2 = __hadd2(l2, *(const __half2*)&u2.x); h2 = __hadd2(h2, *(const __half2*)&u2.y);
            l3 = __hadd2(l3, *(const __half2*)&u3.x); h3 = __hadd2(h3, *(const __half2*)&u3.y);
        }
        for (; e < end; ++e) {
            int r = col[e];
            uint2 u = xs[(r << 4) + c];
            l0 = __hadd2(l0, *(const __half2*)&u.x);
            h0 = __hadd2(h0, *(const __half2*)&u.y);
        }
        // combine the 4 fp16 partial streams in fp32, mean, convert to fp16
        float2 fl0 = __half22float2(l0), fl1 = __half22float2(l1);
        float2 fl2 = __half22float2(l2), fl3 = __half22float2(l3);
        float2 fh0 = __half22float2(h0), fh1 = __half22float2(h1);
        float2 fh2 = __half22float2(h2), fh3 = __half22float2(h3);
        float inv = 1.0f / fmaxf((float)(end - beg), 1.0f);
        half4_t hm;
        hm[0] = (_Float16)(((fl0.x + fl1.x) + (fl2.x + fl3.x)) * inv);
        hm[1] = (_Float16)(((fl0.y + fl1.y) + (fl2.y + fl3.y)) * inv);
        hm[2] = (_Float16)(((fh0.x + fh1.x) + (fh2.x + fh3.x)) * inv);
        hm[3] = (_Float16)(((fh0.y + fh1.y) + (fh2.y + fh3.y)) * inv);
        *((half4_t*)&smh[local][c << 2]) = hm;
        *((uint2*)&sxh[local][c << 2]) = xdu;      // root already fp16
    }
    __syncthreads();   // block-wide: epilogue waves read all 16 nodes

    // ---- MFMA epilogue: this wave computes cols [wave*16, wave*16+16) ----
    int fcol = (wave << 4) + (lane & 15);
    int g4 = lane >> 4;
    const half4_t* BL = (const half4_t*)wl16;
    const half4_t* BR = (const half4_t*)wr16;
    floatx4 acc = {0.f, 0.f, 0.f, 0.f};
#pragma unroll
    for (int ks = 0; ks < 4; ++ks) {
        int ko = (ks << 4) + (g4 << 2);
        half4_t am = *((const half4_t*)&smh[lane & 15][ko]);
        half4_t ax = *((const half4_t*)&sxh[lane & 15][ko]);
        half4_t bw_l = BL[((ks << 2) + g4) * 64 + fcol];
        half4_t bw_r = BR[((ks << 2) + g4) * 64 + fcol];
        acc = __builtin_amdgcn_mfma_f32_16x16x16f16(am, bw_l, acc, 0, 0, 0);
        acc = __builtin_amdgcn_mfma_f32_16x16x16f16(ax, bw_r, acc, 0, 0, 0);
    }
    float bb = bl[fcol];
    int nb0 = bid * 16 + (g4 << 2);   // D row = node local = g4*4 + j
#pragma unroll
    for (int j = 0; j < 4; ++j) {
        int n2 = nb0 + j;
        if (n2 < n_dst) {
            float v = acc[j] + bb;
            if (RELU) v = fmaxf(v, 0.f);
            outh[(size_t)n2 * H + fcol] = __float2half(v);
        }
    }
}

// ---------- classifier: 2 edges per 16-lane group (fp16 features, fp32 dot) ----------
__global__ __launch_bounds__(256) void k_dot(const __half* __restrict__ xu,
                                             const __half* __restrict__ xr,
                                             const int* __restrict__ eli,
                                             float* __restrict__ out, int L) {
    long long wv = (blockIdx.x * 256LL + threadIdx.x) >> 6;
    int lane = threadIdx.x & 63;
    int c = lane & 15, g = lane >> 4;
    long long e0 = wv * 8 + (long long)g * 2;
    if (e0 >= L) return;
    bool two = (e0 + 1 < L);
    int a0 = eli[e0];
    int b0 = eli[(long long)L + e0];
    int a1 = two ? eli[e0 + 1] : a0;
    int b1 = two ? eli[(long long)L + e0 + 1] : b0;
    const uint2* XU = (const uint2*)xu;
    const uint2* XR = (const uint2*)xr;
    uint2 u0 = XU[(a0 << 4) + c];
    uint2 r0 = XR[(b0 << 4) + c];
    uint2 u1 = XU[(a1 << 4) + c];
    uint2 r1 = XR[(b1 << 4) + c];
    float2 ua = __half22float2(*(const __half2*)&u0.x), ub = __half22float2(*(const __half2*)&u0.y);
    float2 ra = __half22float2(*(const __half2*)&r0.x), rb = __half22float2(*(const __half2*)&r0.y);
    float2 va = __half22float2(*(const __half2*)&u1.x), vb = __half22float2(*(const __half2*)&u1.y);
    float2 sa = __half22float2(*(const __half2*)&r1.x), sb = __half22float2(*(const __half2*)&r1.y);
    float p0 = ua.x * ra.x; p0 = fmaf(ua.y, ra.y, p0); p0 = fmaf(ub.x, rb.x, p0); p0 = fmaf(ub.y, rb.y, p0);
    float p1 = va.x * sa.x; p1 = fmaf(va.y, sa.y, p1); p1 = fmaf(vb.x, sb.x, p1); p1 = fmaf(vb.y, sb.y, p1);
#pragma unroll
    for (int off = 1; off < 16; off <<= 1) {
        p0 += __shfl_xor(p0, off);
        p1 += __shfl_xor(p1, off);
    }
    if (c == 0) {
        out[e0] = p0;
        if (two) out[e0 + 1] = p1;
    }
}

extern "C" void kernel_launch(void* const* d_in, const int* in_sizes, int n_in,
                              void* d_out, int out_size, void* d_ws, size_t ws_size,
                              hipStream_t stream) {
    const int*   uid        = (const int*)d_in[0];
    const int*   rid        = (const int*)d_in[1];
    const float* recipe_x   = (const float*)d_in[2];
    const int*   ei         = (const int*)d_in[3];
    const int*   eli        = (const int*)d_in[4];
    const float* user_emb   = (const float*)d_in[5];
    const float* recipe_emb = (const float*)d_in[6];
    const float* lin_w      = (const float*)d_in[7];
    const float* lin_b      = (const float*)d_in[8];
    const float* Wl         = (const float*)d_in[9];
    const float* bl         = (const float*)d_in[10];
    const float* Wr         = (const float*)d_in[11];

    const int Nu = in_sizes[0], Nr = in_sizes[1];
    const int E = in_sizes[3] / 2, L = in_sizes[4] / 2;
    const int nmax = (Nu > Nr) ? Nu : Nr;
    const int W = ((nmax - 1) >> WSH) + 1;   // 196 for N=200000

    char* ws = (char*)d_ws;
    size_t off = 0;
    auto alloc = [&](size_t bytes) -> char* {
        char* p = ws + off;
        off += (bytes + 255) & ~(size_t)255;
        return p;
    };
    // overlay region: bin buffers (dead after k_build_win) share space with the
    // fp16 feature arrays [xh | yh]. No fp32 feature arrays anymore (~136MB total).
    size_t hbytes = ((size_t)Nu + Nr) * H * 2;            // one fp16 feature set
    size_t bbytes = (size_t)E * 8 * 2;                    // bufS,bufD
    size_t rbytes = 2 * hbytes;                           // xh + yh = 102.4MB
    char* region  = alloc(rbytes > bbytes ? rbytes : bbytes);
    __half* xh_user   = (__half*)region;                  // init feats; layer-1 out
    __half* xh_recipe = (__half*)(region + (size_t)Nu * H * 2);
    __half* yh_user   = (__half*)(region + hbytes);       // layer-0 out
    __half* yh_recipe = (__half*)(region + hbytes + (size_t)Nu * H * 2);
    int2* bufS = (int2*)region;
    int2* bufD = (int2*)(region + (size_t)E * 8);
    int* rp_src  = (int*)alloc((size_t)(Nu + 1) * 4);
    int* rp_dst  = (int*)alloc((size_t)(Nr + 1) * 4);
    int* col_src = (int*)alloc((size_t)E * 4);
    int* col_dst = (int*)alloc((size_t)E * 4);
    int* winS  = (int*)alloc(MAXW * 4);      // winS..winD adjacent: one memset
    int* winD  = (int*)alloc(MAXW * 4);
    int* baseS = (int*)alloc((MAXW + 1) * 4);
    int* baseD = (int*)alloc((MAXW + 1) * 4);
    int* curS  = (int*)alloc(MAXW * 4);
    int* curD  = (int*)alloc(MAXW * 4);
    _Float16* w16 = (_Float16*)alloc(8 * 4096 * 2);       // fp16 fragment-order weights
    (void)ws_size; (void)n_in; (void)out_size;

    // zero window counters (ws is poisoned 0xAA)
    hipMemsetAsync(winS, 0, (size_t)2 * MAXW * 4, stream);

    // CSR build: count -> scan -> bin -> fused per-window (deg+scan+scatter)
    k_wincount<<<1024, 256, 0, stream>>>(ei, E, winS, winD);
    k_scan_win<<<1, 256, 0, stream>>>(winS, winD, baseS, baseD, curS, curD);
    k_bin<<<(E + BINCH - 1) / BINCH, 256, 0, stream>>>(ei, E, curS, curD, bufS, bufD);
    k_build_win<<<2 * W, 256, 0, stream>>>(bufS, bufD, baseS, baseD,
                                           rp_src, rp_dst, col_src, col_dst, Nu, Nr, W);

    // weights -> fp16 fragment order; initial features (fp16 only; bufs dead)
    k_prep_w<<<128, 256, 0, stream>>>(Wl, Wr, w16);
    k_init_x<<<(nmax + 3) / 4, 256, 0, stream>>>(uid, rid, recipe_x, user_emb, recipe_emb,
                                                 lin_w, lin_b, xh_user, xh_recipe, Nu, Nr);

    int nbR = (Nr + 15) / 16, nbU = (Nu + 15) / 16;
    // w16 matrix m = layer*4 + rel*2 + lr, each 4096 elements
    // layer 0 (+ReLU): gather xh, root xh; out yh
    k_sage3<true><<<nbR + nbU, 256, 0, stream>>>(
        xh_user, xh_recipe, rp_dst, col_dst, w16 + 0 * 4096, w16 + 1 * 4096,
        bl + 0 * H, yh_recipe, Nr, nbR,
        xh_recipe, xh_user, rp_src, col_src, w16 + 2 * 4096, w16 + 3 * 4096,
        bl + 1 * H, yh_user, Nu);
    // layer 1 (no ReLU): gather yh, root yh; out xh (classifier input)
    k_sage3<false><<<nbR + nbU, 256, 0, stream>>>(
        yh_user, yh_recipe, rp_dst, col_dst, w16 + 4 * 4096, w16 + 5 * 4096,
        bl + 2 * H, xh_recipe, Nr, nbR,
        yh_recipe, yh_user, rp_src, col_src, w16 + 6 * 4096, w16 + 7 * 4096,
        bl + 3 * H, xh_user, Nu);

    // classifier: 32 edges per block
    long long nblk = ((long long)L + 31) / 32;
    k_dot<<<(int)nblk, 256, 0, stream>>>(xh_user, xh_recipe, eli, (float*)d_out, L);
}